// Round 3
// baseline (3054.760 us; speedup 1.0000x reference)
//
#include <hip/hip_runtime.h>

#define FEAT 128
#define BSH 7
#define BNODES 128            // nodes per bucket = 1<<BSH
#define ATILE 4096            // edges per binning block
#define MAXNB 1024            // fast path requires NB <= 1024 (N <= 131072)
#define STILE 1024

// ======================= tiny kernels =======================
__global__ void k_zero_i32(int* __restrict__ p, int n) {
    int i = blockIdx.x * blockDim.x + threadIdx.x;
    if (i < n) p[i] = 0;
}

__global__ void k_count(const int* __restrict__ dst, int* __restrict__ cnt, int E) {
    int i = blockIdx.x * blockDim.x + threadIdx.x;
    if (i < E) atomicAdd(&cnt[dst[i]], 1);
}

__global__ void k_dinv(const int* __restrict__ cnt, float* __restrict__ dinv, int N) {
    int i = blockIdx.x * blockDim.x + threadIdx.x;
    if (i < N) dinv[i] = rsqrtf((float)cnt[i] + 1.0f);
}

__global__ void k_bucket_base(const int* __restrict__ offs, int* __restrict__ cur, int NB) {
    int b = blockIdx.x * blockDim.x + threadIdx.x;
    if (b < NB) cur[b] = offs[b << BSH];
}

// ======================= exclusive scan over cnt -> offs =======================
__global__ void k_scan_partial(const int* __restrict__ cnt, int* __restrict__ part, int N) {
    __shared__ int s[256];
    int base = blockIdx.x * STILE;
    int t = threadIdx.x;
    int sum = 0;
#pragma unroll
    for (int k = 0; k < 4; ++k) {
        int i = base + t * 4 + k;
        if (i < N) sum += cnt[i];
    }
    s[t] = sum; __syncthreads();
    for (int off = 128; off > 0; off >>= 1) {
        if (t < off) s[t] += s[t + off];
        __syncthreads();
    }
    if (t == 0) part[blockIdx.x] = s[0];
}

__global__ void k_scan_top(int* __restrict__ part, int nTiles) {
    __shared__ int s[256];
    int t = threadIdx.x;
    int carry = 0;
    for (int base = 0; base < nTiles; base += 256) {
        int i = base + t;
        int v = (i < nTiles) ? part[i] : 0;
        s[t] = v; __syncthreads();
        for (int o = 1; o < 256; o <<= 1) {
            int add = (t >= o) ? s[t - o] : 0;
            __syncthreads();
            s[t] += add;
            __syncthreads();
        }
        if (i < nTiles) part[i] = (s[t] - v) + carry;
        __syncthreads();
        carry += s[255];
        __syncthreads();
    }
}

__global__ void k_scan_final(const int* __restrict__ cnt, const int* __restrict__ part,
                             int* __restrict__ offs, int N) {
    __shared__ int s[256];
    int base = blockIdx.x * STILE;
    int t = threadIdx.x;
    int v[4]; int sum = 0;
#pragma unroll
    for (int k = 0; k < 4; ++k) {
        int i = base + t * 4 + k;
        v[k] = (i < N) ? cnt[i] : 0;
        sum += v[k];
    }
    s[t] = sum; __syncthreads();
    for (int o = 1; o < 256; o <<= 1) {
        int add = (t >= o) ? s[t - o] : 0;
        __syncthreads();
        s[t] += add;
        __syncthreads();
    }
    int excl = (s[t] - sum) + part[blockIdx.x];
#pragma unroll
    for (int k = 0; k < 4; ++k) {
        int i = base + t * 4 + k;
        if (i < N) offs[i] = excl;
        excl += v[k];
    }
}

// ======================= pass A: bin edges by dst bucket =======================
// pairs[gpos] = (dst_local << 24) | src, grouped by bucket (order within bucket arbitrary)
__global__ __launch_bounds__(256) void k_bin(const int* __restrict__ src,
                                             const int* __restrict__ dst,
                                             int* __restrict__ cur,
                                             unsigned int* __restrict__ pairs,
                                             int E, int NB) {
    __shared__ int hist[MAXNB];
    __shared__ int tbase[MAXNB];
    __shared__ int sc[256];
    __shared__ unsigned int stM[ATILE];
    __shared__ unsigned short stB[ATILE];

    int tid = threadIdx.x;
    int tileBase = blockIdx.x * ATILE;
    int tileCnt = min(ATILE, E - tileBase);

    for (int i = tid; i < NB; i += 256) hist[i] = 0;
    __syncthreads();

    unsigned int pk[16]; unsigned short bk[16]; unsigned short rk[16];
#pragma unroll
    for (int k = 0; k < 16; ++k) {
        int e = tileBase + k * 256 + tid;
        if (e < E) {
            int s = src[e], d = dst[e];
            int b = d >> BSH;
            int r = atomicAdd(&hist[b], 1);
            pk[k] = (unsigned int)s | ((unsigned int)(d & (BNODES - 1)) << 24);
            bk[k] = (unsigned short)b;
            rk[k] = (unsigned short)r;
        }
    }
    __syncthreads();

    // block-wide exclusive scan of hist[0..NB); each thread owns a chunk
    int per = (NB + 255) / 256;
    int myBase = tid * per;
    int partial = 0;
    for (int i = 0; i < per; ++i) {
        int idx = myBase + i;
        if (idx < NB) partial += hist[idx];
    }
    sc[tid] = partial;
    __syncthreads();
    for (int o = 1; o < 256; o <<= 1) {
        int add = (tid >= o) ? sc[tid - o] : 0;
        __syncthreads();
        sc[tid] += add;
        __syncthreads();
    }
    int run = (tid == 0) ? 0 : sc[tid - 1];
    for (int i = 0; i < per; ++i) {
        int idx = myBase + i;
        if (idx < NB) {
            int c = hist[idx];
            hist[idx] = run;                       // exclusive local base
            if (c > 0) {
                int g = atomicAdd(&cur[idx], c);   // reserve run in bucket region
                tbase[idx] = g - run;
            }
            run += c;
        }
    }
    __syncthreads();

#pragma unroll
    for (int k = 0; k < 16; ++k) {
        int e = tileBase + k * 256 + tid;
        if (e < E) {
            int slot = hist[bk[k]] + (int)rk[k];
            stM[slot] = pk[k];
            stB[slot] = bk[k];
        }
    }
    __syncthreads();

    for (int s = tid; s < tileCnt; s += 256) {
        int gpos = tbase[stB[s]] + s;
        pairs[gpos] = stM[s];
    }
}

// ======================= pass B: fused aggregate via LDS accumulators =======================
__global__ __launch_bounds__(512) void k_agg(const float* __restrict__ x,
                                             const float* __restrict__ dinv,
                                             const int* __restrict__ offs,
                                             const unsigned int* __restrict__ pairs,
                                             float* __restrict__ out, int N, int E) {
    __shared__ float acc[BNODES * FEAT];     // 64 KB
    __shared__ uint2 par[512];               // {meta, norm bits}

    int b = blockIdx.x;
    int node0 = b << BSH;
    int nn = min(BNODES, N - node0);
    int tid = threadIdx.x;
    int wave = tid >> 6, lane = tid & 63;

    for (int i = tid; i < BNODES * FEAT / 4; i += 512)
        ((float4*)acc)[i] = make_float4(0.f, 0.f, 0.f, 0.f);

    int start = offs[node0];
    int end = (node0 + BNODES >= N) ? E : offs[node0 + BNODES];
    __syncthreads();

    for (int t0 = start; t0 < end; t0 += 512) {
        int idx = t0 + tid;
        if (idx < end) {
            unsigned int m = pairs[idx];
            int s = m & 0xFFFFFF;
            int dl = (int)(m >> 24);
            float nrm = dinv[s] * dinv[node0 + dl];
            par[tid] = make_uint2(m, __float_as_uint(nrm));
        }
        __syncthreads();
        int cnt = min(512, end - t0);
        int base = wave * 64;
        int mycnt = min(64, max(0, cnt - base));
        for (int e = 0; e < mycnt; ++e) {
            uint2 p = par[base + e];             // wave-uniform -> broadcast
            int s = (int)(p.x & 0xFFFFFF);
            int dl = (int)(p.x >> 24);
            float nrm = __uint_as_float(p.y);
            const float* xs = x + (size_t)s * FEAT;
            float v0 = xs[lane], v1 = xs[lane + 64];
            atomicAdd(&acc[dl * FEAT + lane], nrm * v0);        // 2-way bank alias: free
            atomicAdd(&acc[dl * FEAT + lane + 64], nrm * v1);
        }
        __syncthreads();
    }

    // self-loop + coalesced writeout
    for (int nl = wave; nl < nn; nl += 8) {
        int n = node0 + nl;
        float di = dinv[n];
        float sl = di * di;
        const float* xs = x + (size_t)n * FEAT;
        float* od = out + (size_t)n * FEAT;
        od[lane]      = acc[nl * FEAT + lane]      + sl * xs[lane];
        od[lane + 64] = acc[nl * FEAT + lane + 64] + sl * xs[lane + 64];
    }
}

// ======================= in-place GEMM: out = out @ W + b =======================
__global__ __launch_bounds__(256) void k_gemm_inplace(float* __restrict__ out,
                                                      const float* __restrict__ W,
                                                      const float* __restrict__ b, int N) {
    __shared__ float Wl[FEAT * FEAT];  // 64 KB
    int tid = threadIdx.x;
    for (int i = tid; i < FEAT * FEAT / 4; i += 256)
        ((float4*)Wl)[i] = ((const float4*)W)[i];
    __syncthreads();

    int j = tid & 127;
    int half = tid >> 7;
    int row0 = blockIdx.x * 16 + half * 8;
    row0 = __builtin_amdgcn_readfirstlane(row0);

    float bj = b[j];
    float acc[8];
#pragma unroll
    for (int r = 0; r < 8; ++r) acc[r] = bj;

    const float* Y = out + (size_t)row0 * FEAT;
    bool full = (row0 + 8 <= N);
    if (full) {
#pragma unroll 4
        for (int f = 0; f < FEAT; ++f) {
            float w = Wl[f * FEAT + j];
#pragma unroll
            for (int r = 0; r < 8; ++r) acc[r] += w * Y[(size_t)r * FEAT + f];
        }
    } else {
        for (int f = 0; f < FEAT; ++f) {
            float w = Wl[f * FEAT + j];
            for (int r = 0; r < 8; ++r)
                if (row0 + r < N) acc[r] += w * Y[(size_t)r * FEAT + f];
        }
    }
    __syncthreads();
    if (full) {
#pragma unroll
        for (int r = 0; r < 8; ++r) out[(size_t)(row0 + r) * FEAT + j] = acc[r];
    } else {
        for (int r = 0; r < 8; ++r)
            if (row0 + r < N) out[(size_t)(row0 + r) * FEAT + j] = acc[r];
    }
}

// ======================= fallback (atomic path, tiny ws) =======================
__global__ void k_deg_initf(float* __restrict__ deg, int N) {
    int i = blockIdx.x * blockDim.x + threadIdx.x;
    if (i < N) deg[i] = 1.0f;
}
__global__ void k_deg_countf(const int* __restrict__ dst, float* __restrict__ deg, int E) {
    int i = blockIdx.x * blockDim.x + threadIdx.x;
    if (i < E) atomicAdd(&deg[dst[i]], 1.0f);
}
__global__ void k_rsqrtf_(float* __restrict__ deg, int N) {
    int i = blockIdx.x * blockDim.x + threadIdx.x;
    if (i < N) deg[i] = rsqrtf(deg[i]);
}
__global__ void k_selfloop(const float* __restrict__ x, const float* __restrict__ dinv,
                           float* __restrict__ out, int N) {
    int t = blockIdx.x * blockDim.x + threadIdx.x;
    int n = t >> 5, c = t & 31;
    if (n >= N) return;
    float s = dinv[n]; s *= s;
    float4 v = ((const float4*)(x + (size_t)n * FEAT))[c];
    v.x *= s; v.y *= s; v.z *= s; v.w *= s;
    ((float4*)(out + (size_t)n * FEAT))[c] = v;
}
__global__ void k_scatter(const int* __restrict__ src, const int* __restrict__ dst,
                          const float* __restrict__ dinv, const float* __restrict__ x,
                          float* __restrict__ out, int E) {
    long long gid = (long long)blockIdx.x * blockDim.x + threadIdx.x;
    long long e = gid >> 6;
    int lane = threadIdx.x & 63;
    if (e >= E) return;
    int s = src[e], d = dst[e];
    float nrm = dinv[s] * dinv[d];
    const float* xs = x + (size_t)s * FEAT;
    float* od = out + (size_t)d * FEAT;
    atomicAdd(&od[lane],      nrm * xs[lane]);
    atomicAdd(&od[lane + 64], nrm * xs[lane + 64]);
}

// ======================= launch =======================
extern "C" void kernel_launch(void* const* d_in, const int* in_sizes, int n_in,
                              void* d_out, int out_size, void* d_ws, size_t ws_size,
                              hipStream_t stream) {
    const float* x = (const float*)d_in[0];
    const int*   ei = (const int*)d_in[1];
    const float* W = (const float*)d_in[2];
    const float* b = (const float*)d_in[3];
    float* out = (float*)d_out;

    int N = in_sizes[0] / FEAT;
    int E = in_sizes[1] / 2;
    const int* src = ei;
    const int* dst = ei + E;

    const int bs = 256;
    int nTiles = (N + STILE - 1) / STILE;
    int NB = (N + BNODES - 1) >> BSH;

    // ws: dinv f32[N] | cnt i32[N] | offs i32[N] | part i32[nTiles] | cur i32[NB] | pairs u32[E]
    size_t need = ((size_t)3 * N + nTiles + NB + (size_t)E) * 4;
    bool fast = (ws_size >= need) && (NB <= MAXNB) && (N <= (1 << 24));

    if (fast) {
        float* dinv = (float*)d_ws;
        int* cnt  = (int*)d_ws + N;
        int* offs = (int*)d_ws + 2 * (size_t)N;
        int* part = (int*)d_ws + 3 * (size_t)N;
        int* cur  = (int*)d_ws + 3 * (size_t)N + nTiles;
        unsigned int* pairs = (unsigned int*)((int*)d_ws + 3 * (size_t)N + nTiles + NB);

        k_zero_i32<<<(N + bs - 1) / bs, bs, 0, stream>>>(cnt, N);
        k_count<<<(E + bs - 1) / bs, bs, 0, stream>>>(dst, cnt, E);
        k_dinv<<<(N + bs - 1) / bs, bs, 0, stream>>>(cnt, dinv, N);
        k_scan_partial<<<nTiles, 256, 0, stream>>>(cnt, part, N);
        k_scan_top<<<1, 256, 0, stream>>>(part, nTiles);
        k_scan_final<<<nTiles, 256, 0, stream>>>(cnt, part, offs, N);
        k_bucket_base<<<(NB + bs - 1) / bs, bs, 0, stream>>>(offs, cur, NB);

        int binGrid = (E + ATILE - 1) / ATILE;
        k_bin<<<binGrid, 256, 0, stream>>>(src, dst, cur, pairs, E, NB);
        k_agg<<<NB, 512, 0, stream>>>(x, dinv, offs, pairs, out, N, E);
    } else {
        float* deg = (float*)d_ws;
        k_deg_initf<<<(N + bs - 1) / bs, bs, 0, stream>>>(deg, N);
        k_deg_countf<<<(E + bs - 1) / bs, bs, 0, stream>>>(dst, deg, E);
        k_rsqrtf_<<<(N + bs - 1) / bs, bs, 0, stream>>>(deg, N);
        long long t_sl = (long long)N * 32;
        k_selfloop<<<(int)((t_sl + bs - 1) / bs), bs, 0, stream>>>(x, deg, out, N);
        long long t_sc = (long long)E * 64;
        k_scatter<<<(int)((t_sc + bs - 1) / bs), bs, 0, stream>>>(src, dst, deg, x, out, E);
    }

    k_gemm_inplace<<<(N + 15) / 16, 256, 0, stream>>>(out, W, b, N);
}

// Round 4
// 612.983 us; speedup vs baseline: 4.9834x; 4.9834x over previous
//
#include <hip/hip_runtime.h>

#define FEAT 128
#define BSH 7
#define BNODES 128            // nodes per bucket = 1<<BSH
#define ATILE 4096            // edges per binning block
#define MAXNB 1024            // bin path requires NB <= 1024
#define STILE 1024

// ======================= tiny kernels =======================
__global__ void k_zero_i32(int* __restrict__ p, int n) {
    int i = blockIdx.x * blockDim.x + threadIdx.x;
    if (i < n) p[i] = 0;
}

__global__ void k_count(const int* __restrict__ dst, int* __restrict__ cnt, int E) {
    int i = blockIdx.x * blockDim.x + threadIdx.x;
    if (i < E) atomicAdd(&cnt[dst[i]], 1);
}

__global__ void k_dinv(const int* __restrict__ cnt, float* __restrict__ dinv, int N) {
    int i = blockIdx.x * blockDim.x + threadIdx.x;
    if (i < N) dinv[i] = rsqrtf((float)cnt[i] + 1.0f);
}

__global__ void k_bucket_base(const int* __restrict__ offs, int* __restrict__ cur, int NB) {
    int b = blockIdx.x * blockDim.x + threadIdx.x;
    if (b < NB) cur[b] = offs[b << BSH];
}

// ======================= exclusive scan over cnt -> offs =======================
__global__ void k_scan_partial(const int* __restrict__ cnt, int* __restrict__ part, int N) {
    __shared__ int s[256];
    int base = blockIdx.x * STILE;
    int t = threadIdx.x;
    int sum = 0;
#pragma unroll
    for (int k = 0; k < 4; ++k) {
        int i = base + t * 4 + k;
        if (i < N) sum += cnt[i];
    }
    s[t] = sum; __syncthreads();
    for (int off = 128; off > 0; off >>= 1) {
        if (t < off) s[t] += s[t + off];
        __syncthreads();
    }
    if (t == 0) part[blockIdx.x] = s[0];
}

__global__ void k_scan_top(int* __restrict__ part, int nTiles) {
    __shared__ int s[256];
    int t = threadIdx.x;
    int carry = 0;
    for (int base = 0; base < nTiles; base += 256) {
        int i = base + t;
        int v = (i < nTiles) ? part[i] : 0;
        s[t] = v; __syncthreads();
        for (int o = 1; o < 256; o <<= 1) {
            int add = (t >= o) ? s[t - o] : 0;
            __syncthreads();
            s[t] += add;
            __syncthreads();
        }
        if (i < nTiles) part[i] = (s[t] - v) + carry;
        __syncthreads();
        carry += s[255];
        __syncthreads();
    }
}

__global__ void k_scan_final(const int* __restrict__ cnt, const int* __restrict__ part,
                             int* __restrict__ offs, int N) {
    __shared__ int s[256];
    int base = blockIdx.x * STILE;
    int t = threadIdx.x;
    int v[4]; int sum = 0;
#pragma unroll
    for (int k = 0; k < 4; ++k) {
        int i = base + t * 4 + k;
        v[k] = (i < N) ? cnt[i] : 0;
        sum += v[k];
    }
    s[t] = sum; __syncthreads();
    for (int o = 1; o < 256; o <<= 1) {
        int add = (t >= o) ? s[t - o] : 0;
        __syncthreads();
        s[t] += add;
        __syncthreads();
    }
    int excl = (s[t] - sum) + part[blockIdx.x];
#pragma unroll
    for (int k = 0; k < 4; ++k) {
        int i = base + t * 4 + k;
        if (i < N) offs[i] = excl;
        excl += v[k];
    }
}

// ======================= pass A: bin edges by dst bucket (measured cheap in R3) =======================
// pairs[gpos] = (dst_local << 24) | src, grouped by bucket
__global__ __launch_bounds__(256) void k_bin(const int* __restrict__ src,
                                             const int* __restrict__ dst,
                                             int* __restrict__ cur,
                                             unsigned int* __restrict__ pairs,
                                             int E, int NB) {
    __shared__ int hist[MAXNB];
    __shared__ int tbase[MAXNB];
    __shared__ int sc[256];
    __shared__ unsigned int stM[ATILE];
    __shared__ unsigned short stB[ATILE];

    int tid = threadIdx.x;
    int tileBase = blockIdx.x * ATILE;
    int tileCnt = min(ATILE, E - tileBase);

    for (int i = tid; i < NB; i += 256) hist[i] = 0;
    __syncthreads();

    unsigned int pk[16]; unsigned short bk[16]; unsigned short rk[16];
#pragma unroll
    for (int k = 0; k < 16; ++k) {
        int e = tileBase + k * 256 + tid;
        if (e < E) {
            int s = src[e], d = dst[e];
            int b = d >> BSH;
            int r = atomicAdd(&hist[b], 1);
            pk[k] = (unsigned int)s | ((unsigned int)(d & (BNODES - 1)) << 24);
            bk[k] = (unsigned short)b;
            rk[k] = (unsigned short)r;
        }
    }
    __syncthreads();

    int per = (NB + 255) / 256;
    int myBase = tid * per;
    int partial = 0;
    for (int i = 0; i < per; ++i) {
        int idx = myBase + i;
        if (idx < NB) partial += hist[idx];
    }
    sc[tid] = partial;
    __syncthreads();
    for (int o = 1; o < 256; o <<= 1) {
        int add = (tid >= o) ? sc[tid - o] : 0;
        __syncthreads();
        sc[tid] += add;
        __syncthreads();
    }
    int run = (tid == 0) ? 0 : sc[tid - 1];
    for (int i = 0; i < per; ++i) {
        int idx = myBase + i;
        if (idx < NB) {
            int c = hist[idx];
            hist[idx] = run;
            if (c > 0) {
                int g = atomicAdd(&cur[idx], c);
                tbase[idx] = g - run;
            }
            run += c;
        }
    }
    __syncthreads();

#pragma unroll
    for (int k = 0; k < 16; ++k) {
        int e = tileBase + k * 256 + tid;
        if (e < E) {
            int slot = hist[bk[k]] + (int)rk[k];
            stM[slot] = pk[k];
            stB[slot] = bk[k];
        }
    }
    __syncthreads();

    for (int s = tid; s < tileCnt; s += 256) {
        int gpos = tbase[stB[s]] + s;
        pairs[gpos] = stM[s];
    }
}

// ======================= pass B: bucket-local CSR fill (writes confined to 16 KB window) =======================
__global__ __launch_bounds__(256) void k_fill_local(const unsigned int* __restrict__ pairs,
                                                    const int* __restrict__ offs,
                                                    unsigned int* __restrict__ csr,
                                                    int N, int E) {
    __shared__ int lcur[BNODES];
    int b = blockIdx.x;
    int node0 = b << BSH;
    int nn = min(BNODES, N - node0);
    int tid = threadIdx.x;
    for (int i = tid; i < nn; i += 256) lcur[i] = offs[node0 + i];
    __syncthreads();
    int start = offs[node0];
    int end = (node0 + BNODES >= N) ? E : offs[node0 + BNODES];
    for (int i = start + tid; i < end; i += 256) {
        unsigned int p = pairs[i];
        int dl = (int)(p >> 24);
        int pos = atomicAdd(&lcur[dl], 1);
        csr[pos] = p & 0xFFFFFFu;
    }
}

// ======================= aggregation: one wave per node (measured good in R2) =======================
__global__ __launch_bounds__(256) void k_aggregate(const float* __restrict__ x,
                                                   const float* __restrict__ dinv,
                                                   const int* __restrict__ offs,
                                                   const int* __restrict__ cnt,
                                                   const unsigned int* __restrict__ csr,
                                                   float* __restrict__ out, int N) {
    int wid = (blockIdx.x * blockDim.x + threadIdx.x) >> 6;
    int lane = threadIdx.x & 63;
    if (wid >= N) return;
    int n = __builtin_amdgcn_readfirstlane(wid);

    float di = dinv[n];
    int start = offs[n];
    int m = cnt[n];

    float2 a = ((const float2*)(x + (size_t)n * FEAT))[lane];
    float sl = di * di;
    float2 acc = make_float2(a.x * sl, a.y * sl);

    int i = 0;
    for (; i + 4 <= m; i += 4) {
        int s0 = (int)csr[start + i];
        int s1 = (int)csr[start + i + 1];
        int s2 = (int)csr[start + i + 2];
        int s3 = (int)csr[start + i + 3];
        float n0 = dinv[s0] * di, n1 = dinv[s1] * di, n2 = dinv[s2] * di, n3 = dinv[s3] * di;
        float2 v0 = ((const float2*)(x + (size_t)s0 * FEAT))[lane];
        float2 v1 = ((const float2*)(x + (size_t)s1 * FEAT))[lane];
        float2 v2 = ((const float2*)(x + (size_t)s2 * FEAT))[lane];
        float2 v3 = ((const float2*)(x + (size_t)s3 * FEAT))[lane];
        acc.x += n0 * v0.x; acc.y += n0 * v0.y;
        acc.x += n1 * v1.x; acc.y += n1 * v1.y;
        acc.x += n2 * v2.x; acc.y += n2 * v2.y;
        acc.x += n3 * v3.x; acc.y += n3 * v3.y;
    }
    for (; i < m; ++i) {
        int s0 = (int)csr[start + i];
        float n0 = dinv[s0] * di;
        float2 v0 = ((const float2*)(x + (size_t)s0 * FEAT))[lane];
        acc.x += n0 * v0.x; acc.y += n0 * v0.y;
    }
    ((float2*)(out + (size_t)n * FEAT))[lane] = acc;
}

// ======================= in-place GEMM: out = out @ W + b =======================
__global__ __launch_bounds__(256) void k_gemm_inplace(float* __restrict__ out,
                                                      const float* __restrict__ W,
                                                      const float* __restrict__ b, int N) {
    __shared__ float Wl[FEAT * FEAT];  // 64 KB
    int tid = threadIdx.x;
    for (int i = tid; i < FEAT * FEAT / 4; i += 256)
        ((float4*)Wl)[i] = ((const float4*)W)[i];
    __syncthreads();

    int j = tid & 127;
    int half = tid >> 7;
    int row0 = blockIdx.x * 16 + half * 8;
    row0 = __builtin_amdgcn_readfirstlane(row0);

    float bj = b[j];
    float acc[8];
#pragma unroll
    for (int r = 0; r < 8; ++r) acc[r] = bj;

    const float* Y = out + (size_t)row0 * FEAT;
    bool full = (row0 + 8 <= N);
    if (full) {
#pragma unroll 4
        for (int f = 0; f < FEAT; ++f) {
            float w = Wl[f * FEAT + j];
#pragma unroll
            for (int r = 0; r < 8; ++r) acc[r] += w * Y[(size_t)r * FEAT + f];
        }
    } else {
        for (int f = 0; f < FEAT; ++f) {
            float w = Wl[f * FEAT + j];
            for (int r = 0; r < 8; ++r)
                if (row0 + r < N) acc[r] += w * Y[(size_t)r * FEAT + f];
        }
    }
    __syncthreads();
    if (full) {
#pragma unroll
        for (int r = 0; r < 8; ++r) out[(size_t)(row0 + r) * FEAT + j] = acc[r];
    } else {
        for (int r = 0; r < 8; ++r)
            if (row0 + r < N) out[(size_t)(row0 + r) * FEAT + j] = acc[r];
    }
}

// ======================= fallback: R2 direct fill =======================
__global__ void k_fill_direct(const int* __restrict__ src, const int* __restrict__ dst,
                              int* __restrict__ cur, unsigned int* __restrict__ csr, int E) {
    int e = blockIdx.x * blockDim.x + threadIdx.x;
    if (e < E) {
        int d = dst[e];
        int p = atomicAdd(&cur[d], 1);
        csr[p] = (unsigned int)src[e];
    }
}
__global__ void k_copy_i32(const int* __restrict__ a, int* __restrict__ b, int n) {
    int i = blockIdx.x * blockDim.x + threadIdx.x;
    if (i < n) b[i] = a[i];
}

// ======================= fallback: atomic scatter =======================
__global__ void k_deg_initf(float* __restrict__ deg, int N) {
    int i = blockIdx.x * blockDim.x + threadIdx.x;
    if (i < N) deg[i] = 1.0f;
}
__global__ void k_deg_countf(const int* __restrict__ dst, float* __restrict__ deg, int E) {
    int i = blockIdx.x * blockDim.x + threadIdx.x;
    if (i < E) atomicAdd(&deg[dst[i]], 1.0f);
}
__global__ void k_rsqrtf_(float* __restrict__ deg, int N) {
    int i = blockIdx.x * blockDim.x + threadIdx.x;
    if (i < N) deg[i] = rsqrtf(deg[i]);
}
__global__ void k_selfloop(const float* __restrict__ x, const float* __restrict__ dinv,
                           float* __restrict__ out, int N) {
    int t = blockIdx.x * blockDim.x + threadIdx.x;
    int n = t >> 5, c = t & 31;
    if (n >= N) return;
    float s = dinv[n]; s *= s;
    float4 v = ((const float4*)(x + (size_t)n * FEAT))[c];
    v.x *= s; v.y *= s; v.z *= s; v.w *= s;
    ((float4*)(out + (size_t)n * FEAT))[c] = v;
}
__global__ void k_scatter(const int* __restrict__ src, const int* __restrict__ dst,
                          const float* __restrict__ dinv, const float* __restrict__ x,
                          float* __restrict__ out, int E) {
    long long gid = (long long)blockIdx.x * blockDim.x + threadIdx.x;
    long long e = gid >> 6;
    int lane = threadIdx.x & 63;
    if (e >= E) return;
    int s = src[e], d = dst[e];
    float nrm = dinv[s] * dinv[d];
    const float* xs = x + (size_t)s * FEAT;
    float* od = out + (size_t)d * FEAT;
    atomicAdd(&od[lane],      nrm * xs[lane]);
    atomicAdd(&od[lane + 64], nrm * xs[lane + 64]);
}

// ======================= launch =======================
extern "C" void kernel_launch(void* const* d_in, const int* in_sizes, int n_in,
                              void* d_out, int out_size, void* d_ws, size_t ws_size,
                              hipStream_t stream) {
    const float* x = (const float*)d_in[0];
    const int*   ei = (const int*)d_in[1];
    const float* W = (const float*)d_in[2];
    const float* b = (const float*)d_in[3];
    float* out = (float*)d_out;

    int N = in_sizes[0] / FEAT;
    int E = in_sizes[1] / 2;
    const int* src = ei;
    const int* dst = ei + E;

    const int bs = 256;
    int nTiles = (N + STILE - 1) / STILE;
    int NB = (N + BNODES - 1) >> BSH;

    // ws: dinv f32[N] | cnt i32[N] | offs i32[N] | cur i32[max(N,NB)] | part i32[nTiles] | pairs u32[E] | csr u32[E]
    size_t curN = (size_t)N;  // reserve N for cur so the direct-fill fallback fits the same layout
    size_t need_bin    = (3 * (size_t)N + curN + nTiles + 2 * (size_t)E) * 4;
    size_t need_direct = (3 * (size_t)N + curN + nTiles + (size_t)E) * 4;

    float* dinv = (float*)d_ws;
    int* cnt  = (int*)d_ws + N;
    int* offs = (int*)d_ws + 2 * (size_t)N;
    int* cur  = (int*)d_ws + 3 * (size_t)N;
    int* part = (int*)d_ws + 3 * (size_t)N + curN;
    unsigned int* pairs = (unsigned int*)(part + nTiles);
    unsigned int* csr_bin = pairs + E;      // bin path: csr after pairs
    unsigned int* csr_dir = pairs;          // direct path: csr where pairs would be

    bool can_bin    = (ws_size >= need_bin) && (NB <= MAXNB) && (N <= (1 << 24));
    bool can_direct = (ws_size >= need_direct);

    if (can_bin || can_direct) {
        k_zero_i32<<<(N + bs - 1) / bs, bs, 0, stream>>>(cnt, N);
        k_count<<<(E + bs - 1) / bs, bs, 0, stream>>>(dst, cnt, E);
        k_dinv<<<(N + bs - 1) / bs, bs, 0, stream>>>(cnt, dinv, N);
        k_scan_partial<<<nTiles, 256, 0, stream>>>(cnt, part, N);
        k_scan_top<<<1, 256, 0, stream>>>(part, nTiles);
        k_scan_final<<<nTiles, 256, 0, stream>>>(cnt, part, offs, N);

        unsigned int* csr;
        if (can_bin) {
            csr = csr_bin;
            k_bucket_base<<<(NB + bs - 1) / bs, bs, 0, stream>>>(offs, cur, NB);
            int binGrid = (E + ATILE - 1) / ATILE;
            k_bin<<<binGrid, 256, 0, stream>>>(src, dst, cur, pairs, E, NB);
            k_fill_local<<<NB, 256, 0, stream>>>(pairs, offs, csr, N, E);
        } else {
            csr = csr_dir;
            k_copy_i32<<<(N + bs - 1) / bs, bs, 0, stream>>>(offs, cur, N);
            k_fill_direct<<<(E + bs - 1) / bs, bs, 0, stream>>>(src, dst, cur, csr, E);
        }

        long long t_ag = (long long)N * 64;
        k_aggregate<<<(int)((t_ag + bs - 1) / bs), bs, 0, stream>>>(x, dinv, offs, cnt, csr, out, N);
    } else {
        float* deg = (float*)d_ws;
        k_deg_initf<<<(N + bs - 1) / bs, bs, 0, stream>>>(deg, N);
        k_deg_countf<<<(E + bs - 1) / bs, bs, 0, stream>>>(dst, deg, E);
        k_rsqrtf_<<<(N + bs - 1) / bs, bs, 0, stream>>>(deg, N);
        long long t_sl = (long long)N * 32;
        k_selfloop<<<(int)((t_sl + bs - 1) / bs), bs, 0, stream>>>(x, deg, out, N);
        long long t_sc = (long long)E * 64;
        k_scatter<<<(int)((t_sc + bs - 1) / bs), bs, 0, stream>>>(src, dst, deg, x, out, E);
    }

    k_gemm_inplace<<<(N + 15) / 16, 256, 0, stream>>>(out, W, b, N);
}

// Round 5
// 557.367 us; speedup vs baseline: 5.4807x; 1.0998x over previous
//
#include <hip/hip_runtime.h>

#define FEAT 128
#define BSH 7
#define BNODES 128            // nodes per bucket = 1<<BSH
#define ATILE 4096            // edges per binning block
#define MAXNB 1024            // bin path requires NB <= 1024
#define STILE 1024

// ======================= tiny kernels =======================
__global__ void k_zero_i32(int* __restrict__ p, int n) {
    int i = blockIdx.x * blockDim.x + threadIdx.x;
    if (i < n) p[i] = 0;
}

__global__ void k_count(const int* __restrict__ dst, int* __restrict__ cnt, int E) {
    int i = blockIdx.x * blockDim.x + threadIdx.x;
    if (i < E) atomicAdd(&cnt[dst[i]], 1);
}

__global__ void k_dinv(const int* __restrict__ cnt, float* __restrict__ dinv, int N) {
    int i = blockIdx.x * blockDim.x + threadIdx.x;
    if (i < N) dinv[i] = rsqrtf((float)cnt[i] + 1.0f);
}

__global__ void k_bucket_base(const int* __restrict__ offs, int* __restrict__ cur, int NB) {
    int b = blockIdx.x * blockDim.x + threadIdx.x;
    if (b < NB) cur[b] = offs[b << BSH];
}

// x (fp32) -> xbf (bf16 pairs packed in u32): word k of row = bf(x[2k]) | bf(x[2k+1])<<16
__device__ inline unsigned int f2bf(float f) {
    unsigned int u = __float_as_uint(f);
    return (u + 0x7FFFu + ((u >> 16) & 1u)) >> 16;   // RNE
}
__global__ void k_cvt_bf16(const float* __restrict__ x, unsigned int* __restrict__ xbf,
                           long long n8) {
    long long i = (long long)blockIdx.x * blockDim.x + threadIdx.x;  // one per 8 floats
    if (i >= n8) return;
    float4 a = ((const float4*)x)[i * 2];
    float4 c = ((const float4*)x)[i * 2 + 1];
    uint4 o;
    o.x = f2bf(a.x) | (f2bf(a.y) << 16);
    o.y = f2bf(a.z) | (f2bf(a.w) << 16);
    o.z = f2bf(c.x) | (f2bf(c.y) << 16);
    o.w = f2bf(c.z) | (f2bf(c.w) << 16);
    ((uint4*)xbf)[i] = o;
}

// ======================= exclusive scan over cnt -> offs =======================
__global__ void k_scan_partial(const int* __restrict__ cnt, int* __restrict__ part, int N) {
    __shared__ int s[256];
    int base = blockIdx.x * STILE;
    int t = threadIdx.x;
    int sum = 0;
#pragma unroll
    for (int k = 0; k < 4; ++k) {
        int i = base + t * 4 + k;
        if (i < N) sum += cnt[i];
    }
    s[t] = sum; __syncthreads();
    for (int off = 128; off > 0; off >>= 1) {
        if (t < off) s[t] += s[t + off];
        __syncthreads();
    }
    if (t == 0) part[blockIdx.x] = s[0];
}

__global__ void k_scan_top(int* __restrict__ part, int nTiles) {
    __shared__ int s[256];
    int t = threadIdx.x;
    int carry = 0;
    for (int base = 0; base < nTiles; base += 256) {
        int i = base + t;
        int v = (i < nTiles) ? part[i] : 0;
        s[t] = v; __syncthreads();
        for (int o = 1; o < 256; o <<= 1) {
            int add = (t >= o) ? s[t - o] : 0;
            __syncthreads();
            s[t] += add;
            __syncthreads();
        }
        if (i < nTiles) part[i] = (s[t] - v) + carry;
        __syncthreads();
        carry += s[255];
        __syncthreads();
    }
}

__global__ void k_scan_final(const int* __restrict__ cnt, const int* __restrict__ part,
                             int* __restrict__ offs, int N) {
    __shared__ int s[256];
    int base = blockIdx.x * STILE;
    int t = threadIdx.x;
    int v[4]; int sum = 0;
#pragma unroll
    for (int k = 0; k < 4; ++k) {
        int i = base + t * 4 + k;
        v[k] = (i < N) ? cnt[i] : 0;
        sum += v[k];
    }
    s[t] = sum; __syncthreads();
    for (int o = 1; o < 256; o <<= 1) {
        int add = (t >= o) ? s[t - o] : 0;
        __syncthreads();
        s[t] += add;
        __syncthreads();
    }
    int excl = (s[t] - sum) + part[blockIdx.x];
#pragma unroll
    for (int k = 0; k < 4; ++k) {
        int i = base + t * 4 + k;
        if (i < N) offs[i] = excl;
        excl += v[k];
    }
}

// ======================= pass A: bin edges by dst bucket =======================
__global__ __launch_bounds__(256) void k_bin(const int* __restrict__ src,
                                             const int* __restrict__ dst,
                                             int* __restrict__ cur,
                                             unsigned int* __restrict__ pairs,
                                             int E, int NB) {
    __shared__ int hist[MAXNB];
    __shared__ int tbase[MAXNB];
    __shared__ int sc[256];
    __shared__ unsigned int stM[ATILE];
    __shared__ unsigned short stB[ATILE];

    int tid = threadIdx.x;
    int tileBase = blockIdx.x * ATILE;
    int tileCnt = min(ATILE, E - tileBase);

    for (int i = tid; i < NB; i += 256) hist[i] = 0;
    __syncthreads();

    unsigned int pk[16]; unsigned short bk[16]; unsigned short rk[16];
#pragma unroll
    for (int k = 0; k < 16; ++k) {
        int e = tileBase + k * 256 + tid;
        if (e < E) {
            int s = src[e], d = dst[e];
            int b = d >> BSH;
            int r = atomicAdd(&hist[b], 1);
            pk[k] = (unsigned int)s | ((unsigned int)(d & (BNODES - 1)) << 24);
            bk[k] = (unsigned short)b;
            rk[k] = (unsigned short)r;
        }
    }
    __syncthreads();

    int per = (NB + 255) / 256;
    int myBase = tid * per;
    int partial = 0;
    for (int i = 0; i < per; ++i) {
        int idx = myBase + i;
        if (idx < NB) partial += hist[idx];
    }
    sc[tid] = partial;
    __syncthreads();
    for (int o = 1; o < 256; o <<= 1) {
        int add = (tid >= o) ? sc[tid - o] : 0;
        __syncthreads();
        sc[tid] += add;
        __syncthreads();
    }
    int run = (tid == 0) ? 0 : sc[tid - 1];
    for (int i = 0; i < per; ++i) {
        int idx = myBase + i;
        if (idx < NB) {
            int c = hist[idx];
            hist[idx] = run;
            if (c > 0) {
                int g = atomicAdd(&cur[idx], c);
                tbase[idx] = g - run;
            }
            run += c;
        }
    }
    __syncthreads();

#pragma unroll
    for (int k = 0; k < 16; ++k) {
        int e = tileBase + k * 256 + tid;
        if (e < E) {
            int slot = hist[bk[k]] + (int)rk[k];
            stM[slot] = pk[k];
            stB[slot] = bk[k];
        }
    }
    __syncthreads();

    for (int s = tid; s < tileCnt; s += 256) {
        int gpos = tbase[stB[s]] + s;
        pairs[gpos] = stM[s];
    }
}

// ======================= pass B: bucket-local CSR fill =======================
__global__ __launch_bounds__(256) void k_fill_local(const unsigned int* __restrict__ pairs,
                                                    const int* __restrict__ offs,
                                                    unsigned int* __restrict__ csr,
                                                    int N, int E) {
    __shared__ int lcur[BNODES];
    int b = blockIdx.x;
    int node0 = b << BSH;
    int nn = min(BNODES, N - node0);
    int tid = threadIdx.x;
    for (int i = tid; i < nn; i += 256) lcur[i] = offs[node0 + i];
    __syncthreads();
    int start = offs[node0];
    int end = (node0 + BNODES >= N) ? E : offs[node0 + BNODES];
    for (int i = start + tid; i < end; i += 256) {
        unsigned int p = pairs[i];
        int dl = (int)(p >> 24);
        int pos = atomicAdd(&lcur[dl], 1);
        csr[pos] = p & 0xFFFFFFu;
    }
}

// ======================= aggregation (bf16 gather): one wave per node =======================
__global__ __launch_bounds__(256) void k_aggregate_bf(const float* __restrict__ x,
                                                      const unsigned int* __restrict__ xbf,
                                                      const float* __restrict__ dinv,
                                                      const int* __restrict__ offs,
                                                      const int* __restrict__ cnt,
                                                      const unsigned int* __restrict__ csr,
                                                      float* __restrict__ out, int N) {
    int wid = (blockIdx.x * blockDim.x + threadIdx.x) >> 6;
    int lane = threadIdx.x & 63;
    if (wid >= N) return;
    int n = __builtin_amdgcn_readfirstlane(wid);

    float di = dinv[n];
    int start = offs[n];
    int m = cnt[n];

    // self-loop in fp32
    float2 a = ((const float2*)(x + (size_t)n * FEAT))[lane];
    float sl = di * di;
    float2 acc = make_float2(a.x * sl, a.y * sl);

    int i = 0;
    for (; i + 4 <= m; i += 4) {
        int s0 = (int)csr[start + i];
        int s1 = (int)csr[start + i + 1];
        int s2 = (int)csr[start + i + 2];
        int s3 = (int)csr[start + i + 3];
        float n0 = dinv[s0] * di, n1 = dinv[s1] * di, n2 = dinv[s2] * di, n3 = dinv[s3] * di;
        unsigned int w0 = xbf[(size_t)s0 * 64 + lane];
        unsigned int w1 = xbf[(size_t)s1 * 64 + lane];
        unsigned int w2 = xbf[(size_t)s2 * 64 + lane];
        unsigned int w3 = xbf[(size_t)s3 * 64 + lane];
        acc.x += n0 * __uint_as_float(w0 << 16);
        acc.y += n0 * __uint_as_float(w0 & 0xFFFF0000u);
        acc.x += n1 * __uint_as_float(w1 << 16);
        acc.y += n1 * __uint_as_float(w1 & 0xFFFF0000u);
        acc.x += n2 * __uint_as_float(w2 << 16);
        acc.y += n2 * __uint_as_float(w2 & 0xFFFF0000u);
        acc.x += n3 * __uint_as_float(w3 << 16);
        acc.y += n3 * __uint_as_float(w3 & 0xFFFF0000u);
    }
    for (; i < m; ++i) {
        int s0 = (int)csr[start + i];
        float n0 = dinv[s0] * di;
        unsigned int w0 = xbf[(size_t)s0 * 64 + lane];
        acc.x += n0 * __uint_as_float(w0 << 16);
        acc.y += n0 * __uint_as_float(w0 & 0xFFFF0000u);
    }
    ((float2*)(out + (size_t)n * FEAT))[lane] = acc;
}

// ======================= aggregation (fp32 gather) — fallback =======================
__global__ __launch_bounds__(256) void k_aggregate(const float* __restrict__ x,
                                                   const float* __restrict__ dinv,
                                                   const int* __restrict__ offs,
                                                   const int* __restrict__ cnt,
                                                   const unsigned int* __restrict__ csr,
                                                   float* __restrict__ out, int N) {
    int wid = (blockIdx.x * blockDim.x + threadIdx.x) >> 6;
    int lane = threadIdx.x & 63;
    if (wid >= N) return;
    int n = __builtin_amdgcn_readfirstlane(wid);

    float di = dinv[n];
    int start = offs[n];
    int m = cnt[n];

    float2 a = ((const float2*)(x + (size_t)n * FEAT))[lane];
    float sl = di * di;
    float2 acc = make_float2(a.x * sl, a.y * sl);

    int i = 0;
    for (; i + 4 <= m; i += 4) {
        int s0 = (int)csr[start + i];
        int s1 = (int)csr[start + i + 1];
        int s2 = (int)csr[start + i + 2];
        int s3 = (int)csr[start + i + 3];
        float n0 = dinv[s0] * di, n1 = dinv[s1] * di, n2 = dinv[s2] * di, n3 = dinv[s3] * di;
        float2 v0 = ((const float2*)(x + (size_t)s0 * FEAT))[lane];
        float2 v1 = ((const float2*)(x + (size_t)s1 * FEAT))[lane];
        float2 v2 = ((const float2*)(x + (size_t)s2 * FEAT))[lane];
        float2 v3 = ((const float2*)(x + (size_t)s3 * FEAT))[lane];
        acc.x += n0 * v0.x; acc.y += n0 * v0.y;
        acc.x += n1 * v1.x; acc.y += n1 * v1.y;
        acc.x += n2 * v2.x; acc.y += n2 * v2.y;
        acc.x += n3 * v3.x; acc.y += n3 * v3.y;
    }
    for (; i < m; ++i) {
        int s0 = (int)csr[start + i];
        float n0 = dinv[s0] * di;
        float2 v0 = ((const float2*)(x + (size_t)s0 * FEAT))[lane];
        acc.x += n0 * v0.x; acc.y += n0 * v0.y;
    }
    ((float2*)(out + (size_t)n * FEAT))[lane] = acc;
}

// ======================= in-place GEMM: out = out @ W + b (float4 Y loads) =======================
__global__ __launch_bounds__(256) void k_gemm_inplace(float* __restrict__ out,
                                                      const float* __restrict__ W,
                                                      const float* __restrict__ b, int N) {
    __shared__ float Wl[FEAT * FEAT];  // 64 KB
    int tid = threadIdx.x;
    for (int i = tid; i < FEAT * FEAT / 4; i += 256)
        ((float4*)Wl)[i] = ((const float4*)W)[i];
    __syncthreads();

    int j = tid & 127;
    int half = tid >> 7;
    int row0 = blockIdx.x * 16 + half * 8;
    row0 = __builtin_amdgcn_readfirstlane(row0);

    float bj = b[j];
    float acc[8];
#pragma unroll
    for (int r = 0; r < 8; ++r) acc[r] = bj;

    const float* Y = out + (size_t)row0 * FEAT;
    bool full = (row0 + 8 <= N);
    if (full) {
        for (int f4 = 0; f4 < FEAT; f4 += 4) {
            float w0 = Wl[(f4 + 0) * FEAT + j];
            float w1 = Wl[(f4 + 1) * FEAT + j];
            float w2 = Wl[(f4 + 2) * FEAT + j];
            float w3 = Wl[(f4 + 3) * FEAT + j];
#pragma unroll
            for (int r = 0; r < 8; ++r) {
                float4 y = *(const float4*)&Y[(size_t)r * FEAT + f4];
                acc[r] += w0 * y.x + w1 * y.y + w2 * y.z + w3 * y.w;
            }
        }
    } else {
        for (int f = 0; f < FEAT; ++f) {
            float w = Wl[f * FEAT + j];
            for (int r = 0; r < 8; ++r)
                if (row0 + r < N) acc[r] += w * Y[(size_t)r * FEAT + f];
        }
    }
    __syncthreads();
    if (full) {
#pragma unroll
        for (int r = 0; r < 8; ++r) out[(size_t)(row0 + r) * FEAT + j] = acc[r];
    } else {
        for (int r = 0; r < 8; ++r)
            if (row0 + r < N) out[(size_t)(row0 + r) * FEAT + j] = acc[r];
    }
}

// ======================= fallbacks =======================
__global__ void k_fill_direct(const int* __restrict__ src, const int* __restrict__ dst,
                              int* __restrict__ cur, unsigned int* __restrict__ csr, int E) {
    int e = blockIdx.x * blockDim.x + threadIdx.x;
    if (e < E) {
        int d = dst[e];
        int p = atomicAdd(&cur[d], 1);
        csr[p] = (unsigned int)src[e];
    }
}
__global__ void k_copy_i32(const int* __restrict__ a, int* __restrict__ b, int n) {
    int i = blockIdx.x * blockDim.x + threadIdx.x;
    if (i < n) b[i] = a[i];
}
__global__ void k_deg_initf(float* __restrict__ deg, int N) {
    int i = blockIdx.x * blockDim.x + threadIdx.x;
    if (i < N) deg[i] = 1.0f;
}
__global__ void k_deg_countf(const int* __restrict__ dst, float* __restrict__ deg, int E) {
    int i = blockIdx.x * blockDim.x + threadIdx.x;
    if (i < E) atomicAdd(&deg[dst[i]], 1.0f);
}
__global__ void k_rsqrtf_(float* __restrict__ deg, int N) {
    int i = blockIdx.x * blockDim.x + threadIdx.x;
    if (i < N) deg[i] = rsqrtf(deg[i]);
}
__global__ void k_selfloop(const float* __restrict__ x, const float* __restrict__ dinv,
                           float* __restrict__ out, int N) {
    int t = blockIdx.x * blockDim.x + threadIdx.x;
    int n = t >> 5, c = t & 31;
    if (n >= N) return;
    float s = dinv[n]; s *= s;
    float4 v = ((const float4*)(x + (size_t)n * FEAT))[c];
    v.x *= s; v.y *= s; v.z *= s; v.w *= s;
    ((float4*)(out + (size_t)n * FEAT))[c] = v;
}
__global__ void k_scatter(const int* __restrict__ src, const int* __restrict__ dst,
                          const float* __restrict__ dinv, const float* __restrict__ x,
                          float* __restrict__ out, int E) {
    long long gid = (long long)blockIdx.x * blockDim.x + threadIdx.x;
    long long e = gid >> 6;
    int lane = threadIdx.x & 63;
    if (e >= E) return;
    int s = src[e], d = dst[e];
    float nrm = dinv[s] * dinv[d];
    const float* xs = x + (size_t)s * FEAT;
    float* od = out + (size_t)d * FEAT;
    atomicAdd(&od[lane],      nrm * xs[lane]);
    atomicAdd(&od[lane + 64], nrm * xs[lane + 64]);
}

// ======================= launch =======================
extern "C" void kernel_launch(void* const* d_in, const int* in_sizes, int n_in,
                              void* d_out, int out_size, void* d_ws, size_t ws_size,
                              hipStream_t stream) {
    const float* x = (const float*)d_in[0];
    const int*   ei = (const int*)d_in[1];
    const float* W = (const float*)d_in[2];
    const float* b = (const float*)d_in[3];
    float* out = (float*)d_out;

    int N = in_sizes[0] / FEAT;
    int E = in_sizes[1] / 2;
    const int* src = ei;
    const int* dst = ei + E;

    const int bs = 256;
    int nTiles = (N + STILE - 1) / STILE;
    int NB = (N + BNODES - 1) >> BSH;

    // ws: dinv f32[N] | cnt i32[N] | offs i32[N] | cur i32[N] | part i32[nTiles]
    //     | pairs u32[E] | csr u32[E] | xbf u32[N*64]
    size_t need_direct = (4 * (size_t)N + nTiles + (size_t)E) * 4;
    size_t need_bin    = (4 * (size_t)N + nTiles + 2 * (size_t)E) * 4;
    size_t need_bf     = need_bin + (size_t)N * 64 * 4;

    float* dinv = (float*)d_ws;
    int* cnt  = (int*)d_ws + N;
    int* offs = (int*)d_ws + 2 * (size_t)N;
    int* cur  = (int*)d_ws + 3 * (size_t)N;
    int* part = (int*)d_ws + 4 * (size_t)N;
    unsigned int* pairs = (unsigned int*)(part + nTiles);
    unsigned int* csr_bin = pairs + E;
    unsigned int* xbf = csr_bin + E;
    unsigned int* csr_dir = pairs;

    bool can_bin    = (ws_size >= need_bin) && (NB <= MAXNB) && (N <= (1 << 24));
    bool can_bf     = can_bin && (ws_size >= need_bf);
    bool can_direct = (ws_size >= need_direct);

    if (can_bin || can_direct) {
        k_zero_i32<<<(N + bs - 1) / bs, bs, 0, stream>>>(cnt, N);
        k_count<<<(E + bs - 1) / bs, bs, 0, stream>>>(dst, cnt, E);
        k_dinv<<<(N + bs - 1) / bs, bs, 0, stream>>>(cnt, dinv, N);
        k_scan_partial<<<nTiles, 256, 0, stream>>>(cnt, part, N);
        k_scan_top<<<1, 256, 0, stream>>>(part, nTiles);
        k_scan_final<<<nTiles, 256, 0, stream>>>(cnt, part, offs, N);

        unsigned int* csr;
        if (can_bin) {
            csr = csr_bin;
            k_bucket_base<<<(NB + bs - 1) / bs, bs, 0, stream>>>(offs, cur, NB);
            int binGrid = (E + ATILE - 1) / ATILE;
            k_bin<<<binGrid, 256, 0, stream>>>(src, dst, cur, pairs, E, NB);
            k_fill_local<<<NB, 256, 0, stream>>>(pairs, offs, csr, N, E);
        } else {
            csr = csr_dir;
            k_copy_i32<<<(N + bs - 1) / bs, bs, 0, stream>>>(offs, cur, N);
            k_fill_direct<<<(E + bs - 1) / bs, bs, 0, stream>>>(src, dst, cur, csr, E);
        }

        long long t_ag = (long long)N * 64;
        if (can_bf) {
            long long n8 = (long long)N * (FEAT / 8);
            k_cvt_bf16<<<(int)((n8 + bs - 1) / bs), bs, 0, stream>>>(x, xbf, n8);
            k_aggregate_bf<<<(int)((t_ag + bs - 1) / bs), bs, 0, stream>>>(
                x, xbf, dinv, offs, cnt, csr, out, N);
        } else {
            k_aggregate<<<(int)((t_ag + bs - 1) / bs), bs, 0, stream>>>(
                x, dinv, offs, cnt, csr, out, N);
        }
    } else {
        float* deg = (float*)d_ws;
        k_deg_initf<<<(N + bs - 1) / bs, bs, 0, stream>>>(deg, N);
        k_deg_countf<<<(E + bs - 1) / bs, bs, 0, stream>>>(dst, deg, E);
        k_rsqrtf_<<<(N + bs - 1) / bs, bs, 0, stream>>>(deg, N);
        long long t_sl = (long long)N * 32;
        k_selfloop<<<(int)((t_sl + bs - 1) / bs), bs, 0, stream>>>(x, deg, out, N);
        long long t_sc = (long long)E * 64;
        k_scatter<<<(int)((t_sc + bs - 1) / bs), bs, 0, stream>>>(src, dst, deg, x, out, E);
    }

    k_gemm_inplace<<<(N + 15) / 16, 256, 0, stream>>>(out, W, b, N);
}

// Round 6
// 455.883 us; speedup vs baseline: 6.7008x; 1.2226x over previous
//
#include <hip/hip_runtime.h>

#define FEAT 128
#define BSH 7
#define BNODES 128            // nodes per bucket = 1<<BSH
#define ATILE 4096            // edges per binning block
#define MAXNB 1024            // bin path requires NB <= 1024
#define STILE 1024

typedef __attribute__((ext_vector_type(8))) short bf16x8;
typedef __attribute__((ext_vector_type(4))) float f32x4;

// ======================= tiny kernels =======================
__global__ void k_zero_i32(int* __restrict__ p, int n) {
    int i = blockIdx.x * blockDim.x + threadIdx.x;
    if (i < n) p[i] = 0;
}

__global__ void k_count(const int* __restrict__ dst, int* __restrict__ cnt, int E) {
    int i = blockIdx.x * blockDim.x + threadIdx.x;
    if (i < E) atomicAdd(&cnt[dst[i]], 1);
}

__global__ void k_dinv(const int* __restrict__ cnt, float* __restrict__ dinv, int N) {
    int i = blockIdx.x * blockDim.x + threadIdx.x;
    if (i < N) dinv[i] = rsqrtf((float)cnt[i] + 1.0f);
}

__global__ void k_bucket_base(const int* __restrict__ offs, int* __restrict__ cur, int NB) {
    int b = blockIdx.x * blockDim.x + threadIdx.x;
    if (b < NB) cur[b] = offs[b << BSH];
}

__device__ inline unsigned int f2bf(float f) {
    unsigned int u = __float_as_uint(f);
    return (u + 0x7FFFu + ((u >> 16) & 1u)) >> 16;   // RNE
}

__global__ void k_cvt_bf16(const float* __restrict__ x, unsigned int* __restrict__ xbf,
                           long long n8) {
    long long i = (long long)blockIdx.x * blockDim.x + threadIdx.x;  // one per 8 floats
    if (i >= n8) return;
    float4 a = ((const float4*)x)[i * 2];
    float4 c = ((const float4*)x)[i * 2 + 1];
    uint4 o;
    o.x = f2bf(a.x) | (f2bf(a.y) << 16);
    o.y = f2bf(a.z) | (f2bf(a.w) << 16);
    o.z = f2bf(c.x) | (f2bf(c.y) << 16);
    o.w = f2bf(c.z) | (f2bf(c.w) << 16);
    ((uint4*)xbf)[i] = o;
}

// Wt[n][k] = bf16(W[k][n]) — 128x128, one tiny kernel
__global__ void k_cvt_w(const float* __restrict__ W, unsigned short* __restrict__ wt) {
    int i = blockIdx.x * blockDim.x + threadIdx.x;
    if (i >= FEAT * FEAT) return;
    int n = i >> 7, k = i & 127;
    wt[i] = (unsigned short)f2bf(W[k * FEAT + n]);
}

// ======================= exclusive scan over cnt -> offs =======================
__global__ void k_scan_partial(const int* __restrict__ cnt, int* __restrict__ part, int N) {
    __shared__ int s[256];
    int base = blockIdx.x * STILE;
    int t = threadIdx.x;
    int sum = 0;
#pragma unroll
    for (int k = 0; k < 4; ++k) {
        int i = base + t * 4 + k;
        if (i < N) sum += cnt[i];
    }
    s[t] = sum; __syncthreads();
    for (int off = 128; off > 0; off >>= 1) {
        if (t < off) s[t] += s[t + off];
        __syncthreads();
    }
    if (t == 0) part[blockIdx.x] = s[0];
}

__global__ void k_scan_top(int* __restrict__ part, int nTiles) {
    __shared__ int s[256];
    int t = threadIdx.x;
    int carry = 0;
    for (int base = 0; base < nTiles; base += 256) {
        int i = base + t;
        int v = (i < nTiles) ? part[i] : 0;
        s[t] = v; __syncthreads();
        for (int o = 1; o < 256; o <<= 1) {
            int add = (t >= o) ? s[t - o] : 0;
            __syncthreads();
            s[t] += add;
            __syncthreads();
        }
        if (i < nTiles) part[i] = (s[t] - v) + carry;
        __syncthreads();
        carry += s[255];
        __syncthreads();
    }
}

__global__ void k_scan_final(const int* __restrict__ cnt, const int* __restrict__ part,
                             int* __restrict__ offs, int N) {
    __shared__ int s[256];
    int base = blockIdx.x * STILE;
    int t = threadIdx.x;
    int v[4]; int sum = 0;
#pragma unroll
    for (int k = 0; k < 4; ++k) {
        int i = base + t * 4 + k;
        v[k] = (i < N) ? cnt[i] : 0;
        sum += v[k];
    }
    s[t] = sum; __syncthreads();
    for (int o = 1; o < 256; o <<= 1) {
        int add = (t >= o) ? s[t - o] : 0;
        __syncthreads();
        s[t] += add;
        __syncthreads();
    }
    int excl = (s[t] - sum) + part[blockIdx.x];
#pragma unroll
    for (int k = 0; k < 4; ++k) {
        int i = base + t * 4 + k;
        if (i < N) offs[i] = excl;
        excl += v[k];
    }
}

// ======================= pass A: bin edges by dst bucket =======================
__global__ __launch_bounds__(256) void k_bin(const int* __restrict__ src,
                                             const int* __restrict__ dst,
                                             int* __restrict__ cur,
                                             unsigned int* __restrict__ pairs,
                                             int E, int NB) {
    __shared__ int hist[MAXNB];
    __shared__ int tbase[MAXNB];
    __shared__ int sc[256];
    __shared__ unsigned int stM[ATILE];
    __shared__ unsigned short stB[ATILE];

    int tid = threadIdx.x;
    int tileBase = blockIdx.x * ATILE;
    int tileCnt = min(ATILE, E - tileBase);

    for (int i = tid; i < NB; i += 256) hist[i] = 0;
    __syncthreads();

    unsigned int pk[16]; unsigned short bk[16]; unsigned short rk[16];
#pragma unroll
    for (int k = 0; k < 16; ++k) {
        int e = tileBase + k * 256 + tid;
        if (e < E) {
            int s = src[e], d = dst[e];
            int b = d >> BSH;
            int r = atomicAdd(&hist[b], 1);
            pk[k] = (unsigned int)s | ((unsigned int)(d & (BNODES - 1)) << 24);
            bk[k] = (unsigned short)b;
            rk[k] = (unsigned short)r;
        }
    }
    __syncthreads();

    int per = (NB + 255) / 256;
    int myBase = tid * per;
    int partial = 0;
    for (int i = 0; i < per; ++i) {
        int idx = myBase + i;
        if (idx < NB) partial += hist[idx];
    }
    sc[tid] = partial;
    __syncthreads();
    for (int o = 1; o < 256; o <<= 1) {
        int add = (tid >= o) ? sc[tid - o] : 0;
        __syncthreads();
        sc[tid] += add;
        __syncthreads();
    }
    int run = (tid == 0) ? 0 : sc[tid - 1];
    for (int i = 0; i < per; ++i) {
        int idx = myBase + i;
        if (idx < NB) {
            int c = hist[idx];
            hist[idx] = run;
            if (c > 0) {
                int g = atomicAdd(&cur[idx], c);
                tbase[idx] = g - run;
            }
            run += c;
        }
    }
    __syncthreads();

#pragma unroll
    for (int k = 0; k < 16; ++k) {
        int e = tileBase + k * 256 + tid;
        if (e < E) {
            int slot = hist[bk[k]] + (int)rk[k];
            stM[slot] = pk[k];
            stB[slot] = bk[k];
        }
    }
    __syncthreads();

    for (int s = tid; s < tileCnt; s += 256) {
        int gpos = tbase[stB[s]] + s;
        pairs[gpos] = stM[s];
    }
}

// ======================= pass B: bucket-local CSR fill =======================
__global__ __launch_bounds__(256) void k_fill_local(const unsigned int* __restrict__ pairs,
                                                    const int* __restrict__ offs,
                                                    unsigned int* __restrict__ csr,
                                                    int N, int E) {
    __shared__ int lcur[BNODES];
    int b = blockIdx.x;
    int node0 = b << BSH;
    int nn = min(BNODES, N - node0);
    int tid = threadIdx.x;
    for (int i = tid; i < nn; i += 256) lcur[i] = offs[node0 + i];
    __syncthreads();
    int start = offs[node0];
    int end = (node0 + BNODES >= N) ? E : offs[node0 + BNODES];
    for (int i = start + tid; i < end; i += 256) {
        unsigned int p = pairs[i];
        int dl = (int)(p >> 24);
        int pos = atomicAdd(&lcur[dl], 1);
        csr[pos] = p & 0xFFFFFFu;
    }
}

// ======================= aggregation (bf16 gather): one wave per node, unroll 8 =======================
__global__ __launch_bounds__(256) void k_aggregate_bf(const float* __restrict__ x,
                                                      const unsigned int* __restrict__ xbf,
                                                      const float* __restrict__ dinv,
                                                      const int* __restrict__ offs,
                                                      const int* __restrict__ cnt,
                                                      const unsigned int* __restrict__ csr,
                                                      float* __restrict__ out, int N) {
    int wid = (blockIdx.x * blockDim.x + threadIdx.x) >> 6;
    int lane = threadIdx.x & 63;
    if (wid >= N) return;
    int n = __builtin_amdgcn_readfirstlane(wid);

    float di = dinv[n];
    int start = offs[n];
    int m = cnt[n];

    // self-loop in fp32
    float2 a = ((const float2*)(x + (size_t)n * FEAT))[lane];
    float sl = di * di;
    float2 acc = make_float2(a.x * sl, a.y * sl);

    int i = 0;
    for (; i + 8 <= m; i += 8) {
        int s[8]; float nr[8]; unsigned int w[8];
#pragma unroll
        for (int u = 0; u < 8; ++u) s[u] = (int)csr[start + i + u];
#pragma unroll
        for (int u = 0; u < 8; ++u) w[u] = xbf[(size_t)s[u] * 64 + lane];
#pragma unroll
        for (int u = 0; u < 8; ++u) nr[u] = dinv[s[u]] * di;
#pragma unroll
        for (int u = 0; u < 8; ++u) {
            acc.x += nr[u] * __uint_as_float(w[u] << 16);
            acc.y += nr[u] * __uint_as_float(w[u] & 0xFFFF0000u);
        }
    }
    for (; i + 4 <= m; i += 4) {
        int s0 = (int)csr[start + i];
        int s1 = (int)csr[start + i + 1];
        int s2 = (int)csr[start + i + 2];
        int s3 = (int)csr[start + i + 3];
        float n0 = dinv[s0] * di, n1 = dinv[s1] * di, n2 = dinv[s2] * di, n3 = dinv[s3] * di;
        unsigned int w0 = xbf[(size_t)s0 * 64 + lane];
        unsigned int w1 = xbf[(size_t)s1 * 64 + lane];
        unsigned int w2 = xbf[(size_t)s2 * 64 + lane];
        unsigned int w3 = xbf[(size_t)s3 * 64 + lane];
        acc.x += n0 * __uint_as_float(w0 << 16);
        acc.y += n0 * __uint_as_float(w0 & 0xFFFF0000u);
        acc.x += n1 * __uint_as_float(w1 << 16);
        acc.y += n1 * __uint_as_float(w1 & 0xFFFF0000u);
        acc.x += n2 * __uint_as_float(w2 << 16);
        acc.y += n2 * __uint_as_float(w2 & 0xFFFF0000u);
        acc.x += n3 * __uint_as_float(w3 << 16);
        acc.y += n3 * __uint_as_float(w3 & 0xFFFF0000u);
    }
    for (; i < m; ++i) {
        int s0 = (int)csr[start + i];
        float n0 = dinv[s0] * di;
        unsigned int w0 = xbf[(size_t)s0 * 64 + lane];
        acc.x += n0 * __uint_as_float(w0 << 16);
        acc.y += n0 * __uint_as_float(w0 & 0xFFFF0000u);
    }
    ((float2*)(out + (size_t)n * FEAT))[lane] = acc;
}

// ======================= aggregation (fp32 gather) — fallback =======================
__global__ __launch_bounds__(256) void k_aggregate(const float* __restrict__ x,
                                                   const float* __restrict__ dinv,
                                                   const int* __restrict__ offs,
                                                   const int* __restrict__ cnt,
                                                   const unsigned int* __restrict__ csr,
                                                   float* __restrict__ out, int N) {
    int wid = (blockIdx.x * blockDim.x + threadIdx.x) >> 6;
    int lane = threadIdx.x & 63;
    if (wid >= N) return;
    int n = __builtin_amdgcn_readfirstlane(wid);

    float di = dinv[n];
    int start = offs[n];
    int m = cnt[n];

    float2 a = ((const float2*)(x + (size_t)n * FEAT))[lane];
    float sl = di * di;
    float2 acc = make_float2(a.x * sl, a.y * sl);

    int i = 0;
    for (; i + 4 <= m; i += 4) {
        int s0 = (int)csr[start + i];
        int s1 = (int)csr[start + i + 1];
        int s2 = (int)csr[start + i + 2];
        int s3 = (int)csr[start + i + 3];
        float n0 = dinv[s0] * di, n1 = dinv[s1] * di, n2 = dinv[s2] * di, n3 = dinv[s3] * di;
        float2 v0 = ((const float2*)(x + (size_t)s0 * FEAT))[lane];
        float2 v1 = ((const float2*)(x + (size_t)s1 * FEAT))[lane];
        float2 v2 = ((const float2*)(x + (size_t)s2 * FEAT))[lane];
        float2 v3 = ((const float2*)(x + (size_t)s3 * FEAT))[lane];
        acc.x += n0 * v0.x; acc.y += n0 * v0.y;
        acc.x += n1 * v1.x; acc.y += n1 * v1.y;
        acc.x += n2 * v2.x; acc.y += n2 * v2.y;
        acc.x += n3 * v3.x; acc.y += n3 * v3.y;
    }
    for (; i < m; ++i) {
        int s0 = (int)csr[start + i];
        float n0 = dinv[s0] * di;
        float2 v0 = ((const float2*)(x + (size_t)s0 * FEAT))[lane];
        acc.x += n0 * v0.x; acc.y += n0 * v0.y;
    }
    ((float2*)(out + (size_t)n * FEAT))[lane] = acc;
}

// ======================= MFMA GEMM (in-place): out = bf16(out) @ Wt^T + b =======================
// block: 128 rows; 4 waves x (2 mtiles x 8 ntiles) of 16x16, K=128 in 4 steps of 32.
// A: fp32 out rows -> bf16 in-register. B: Wt[n][k] bf16, contiguous 16B frags.
// In-place safe: each wave reads only its own 32 rows; all reads feed mfma before stores.
__global__ __launch_bounds__(256) void k_gemm_mfma(float* __restrict__ out,
                                                   const unsigned short* __restrict__ wt,
                                                   const float* __restrict__ b, int N) {
    int tid = threadIdx.x;
    int wave = tid >> 6, l = tid & 63;
    int lm = l & 15, lg = l >> 4;
    int rowA = blockIdx.x * 128 + wave * 32;

    f32x4 acc[2][8];
#pragma unroll
    for (int mt = 0; mt < 2; ++mt)
#pragma unroll
        for (int nt = 0; nt < 8; ++nt)
            acc[mt][nt] = (f32x4){0.f, 0.f, 0.f, 0.f};

#pragma unroll
    for (int kk = 0; kk < 4; ++kk) {
        int k = kk * 32 + lg * 8;
        bf16x8 afr[2];
#pragma unroll
        for (int mt = 0; mt < 2; ++mt) {
            int r = rowA + mt * 16 + lm;
            float4 f0 = make_float4(0.f, 0.f, 0.f, 0.f);
            float4 f1 = make_float4(0.f, 0.f, 0.f, 0.f);
            if (r < N) {
                const float* p = out + (size_t)r * FEAT + k;
                f0 = *(const float4*)p;
                f1 = *(const float4*)(p + 4);
            }
            afr[mt][0] = (short)f2bf(f0.x);
            afr[mt][1] = (short)f2bf(f0.y);
            afr[mt][2] = (short)f2bf(f0.z);
            afr[mt][3] = (short)f2bf(f0.w);
            afr[mt][4] = (short)f2bf(f1.x);
            afr[mt][5] = (short)f2bf(f1.y);
            afr[mt][6] = (short)f2bf(f1.z);
            afr[mt][7] = (short)f2bf(f1.w);
        }
#pragma unroll
        for (int nt = 0; nt < 8; ++nt) {
            int col = nt * 16 + lm;
            bf16x8 bfr = *(const bf16x8*)(wt + (size_t)col * FEAT + k);
            acc[0][nt] = __builtin_amdgcn_mfma_f32_16x16x32_bf16(afr[0], bfr, acc[0][nt], 0, 0, 0);
            acc[1][nt] = __builtin_amdgcn_mfma_f32_16x16x32_bf16(afr[1], bfr, acc[1][nt], 0, 0, 0);
        }
    }

#pragma unroll
    for (int nt = 0; nt < 8; ++nt) {
        int col = nt * 16 + lm;
        float bv = b[col];
#pragma unroll
        for (int mt = 0; mt < 2; ++mt) {
#pragma unroll
            for (int r = 0; r < 4; ++r) {
                int row = rowA + mt * 16 + lg * 4 + r;
                if (row < N) out[(size_t)row * FEAT + col] = acc[mt][nt][r] + bv;
            }
        }
    }
}

// ======================= fp32 GEMM (fallback paths) =======================
__global__ __launch_bounds__(256) void k_gemm_inplace(float* __restrict__ out,
                                                      const float* __restrict__ W,
                                                      const float* __restrict__ b, int N) {
    __shared__ float Wl[FEAT * FEAT];  // 64 KB
    int tid = threadIdx.x;
    for (int i = tid; i < FEAT * FEAT / 4; i += 256)
        ((float4*)Wl)[i] = ((const float4*)W)[i];
    __syncthreads();

    int j = tid & 127;
    int half = tid >> 7;
    int row0 = blockIdx.x * 16 + half * 8;
    row0 = __builtin_amdgcn_readfirstlane(row0);

    float bj = b[j];
    float acc[8];
#pragma unroll
    for (int r = 0; r < 8; ++r) acc[r] = bj;

    const float* Y = out + (size_t)row0 * FEAT;
    bool full = (row0 + 8 <= N);
    if (full) {
        for (int f4 = 0; f4 < FEAT; f4 += 4) {
            float w0 = Wl[(f4 + 0) * FEAT + j];
            float w1 = Wl[(f4 + 1) * FEAT + j];
            float w2 = Wl[(f4 + 2) * FEAT + j];
            float w3 = Wl[(f4 + 3) * FEAT + j];
#pragma unroll
            for (int r = 0; r < 8; ++r) {
                float4 y = *(const float4*)&Y[(size_t)r * FEAT + f4];
                acc[r] += w0 * y.x + w1 * y.y + w2 * y.z + w3 * y.w;
            }
        }
    } else {
        for (int f = 0; f < FEAT; ++f) {
            float w = Wl[f * FEAT + j];
            for (int r = 0; r < 8; ++r)
                if (row0 + r < N) acc[r] += w * Y[(size_t)r * FEAT + f];
        }
    }
    __syncthreads();
    if (full) {
#pragma unroll
        for (int r = 0; r < 8; ++r) out[(size_t)(row0 + r) * FEAT + j] = acc[r];
    } else {
        for (int r = 0; r < 8; ++r)
            if (row0 + r < N) out[(size_t)(row0 + r) * FEAT + j] = acc[r];
    }
}

// ======================= fallbacks =======================
__global__ void k_fill_direct(const int* __restrict__ src, const int* __restrict__ dst,
                              int* __restrict__ cur, unsigned int* __restrict__ csr, int E) {
    int e = blockIdx.x * blockDim.x + threadIdx.x;
    if (e < E) {
        int d = dst[e];
        int p = atomicAdd(&cur[d], 1);
        csr[p] = (unsigned int)src[e];
    }
}
__global__ void k_copy_i32(const int* __restrict__ a, int* __restrict__ b, int n) {
    int i = blockIdx.x * blockDim.x + threadIdx.x;
    if (i < n) b[i] = a[i];
}
__global__ void k_deg_initf(float* __restrict__ deg, int N) {
    int i = blockIdx.x * blockDim.x + threadIdx.x;
    if (i < N) deg[i] = 1.0f;
}
__global__ void k_deg_countf(const int* __restrict__ dst, float* __restrict__ deg, int E) {
    int i = blockIdx.x * blockDim.x + threadIdx.x;
    if (i < E) atomicAdd(&deg[dst[i]], 1.0f);
}
__global__ void k_rsqrtf_(float* __restrict__ deg, int N) {
    int i = blockIdx.x * blockDim.x + threadIdx.x;
    if (i < N) deg[i] = rsqrtf(deg[i]);
}
__global__ void k_selfloop(const float* __restrict__ x, const float* __restrict__ dinv,
                           float* __restrict__ out, int N) {
    int t = blockIdx.x * blockDim.x + threadIdx.x;
    int n = t >> 5, c = t & 31;
    if (n >= N) return;
    float s = dinv[n]; s *= s;
    float4 v = ((const float4*)(x + (size_t)n * FEAT))[c];
    v.x *= s; v.y *= s; v.z *= s; v.w *= s;
    ((float4*)(out + (size_t)n * FEAT))[c] = v;
}
__global__ void k_scatter(const int* __restrict__ src, const int* __restrict__ dst,
                          const float* __restrict__ dinv, const float* __restrict__ x,
                          float* __restrict__ out, int E) {
    long long gid = (long long)blockIdx.x * blockDim.x + threadIdx.x;
    long long e = gid >> 6;
    int lane = threadIdx.x & 63;
    if (e >= E) return;
    int s = src[e], d = dst[e];
    float nrm = dinv[s] * dinv[d];
    const float* xs = x + (size_t)s * FEAT;
    float* od = out + (size_t)d * FEAT;
    atomicAdd(&od[lane],      nrm * xs[lane]);
    atomicAdd(&od[lane + 64], nrm * xs[lane + 64]);
}

// ======================= launch =======================
extern "C" void kernel_launch(void* const* d_in, const int* in_sizes, int n_in,
                              void* d_out, int out_size, void* d_ws, size_t ws_size,
                              hipStream_t stream) {
    const float* x = (const float*)d_in[0];
    const int*   ei = (const int*)d_in[1];
    const float* W = (const float*)d_in[2];
    const float* b = (const float*)d_in[3];
    float* out = (float*)d_out;

    int N = in_sizes[0] / FEAT;
    int E = in_sizes[1] / 2;
    const int* src = ei;
    const int* dst = ei + E;

    const int bs = 256;
    int nTiles = (N + STILE - 1) / STILE;
    int NB = (N + BNODES - 1) >> BSH;

    // ws: dinv f32[N] | cnt i32[N] | offs i32[N] | cur i32[N] | part i32[nTiles]
    //     | pairs u32[E] | csr u32[E] | xbf u32[N*64] | wbf u16[128*128]
    size_t need_direct = (4 * (size_t)N + nTiles + (size_t)E) * 4;
    size_t need_bin    = (4 * (size_t)N + nTiles + 2 * (size_t)E) * 4;
    size_t need_bf     = need_bin + (size_t)N * 64 * 4 + (size_t)FEAT * FEAT * 2;

    float* dinv = (float*)d_ws;
    int* cnt  = (int*)d_ws + N;
    int* offs = (int*)d_ws + 2 * (size_t)N;
    int* cur  = (int*)d_ws + 3 * (size_t)N;
    int* part = (int*)d_ws + 4 * (size_t)N;
    unsigned int* pairs = (unsigned int*)(part + nTiles);
    unsigned int* csr_bin = pairs + E;
    unsigned int* xbf = csr_bin + E;
    unsigned short* wbf = (unsigned short*)(xbf + (size_t)N * 64);
    unsigned int* csr_dir = pairs;

    bool can_bin    = (ws_size >= need_bin) && (NB <= MAXNB) && (N <= (1 << 24));
    bool can_bf     = can_bin && (ws_size >= need_bf);
    bool can_direct = (ws_size >= need_direct);

    if (can_bin || can_direct) {
        k_zero_i32<<<(N + bs - 1) / bs, bs, 0, stream>>>(cnt, N);
        k_count<<<(E + bs - 1) / bs, bs, 0, stream>>>(dst, cnt, E);
        k_dinv<<<(N + bs - 1) / bs, bs, 0, stream>>>(cnt, dinv, N);
        k_scan_partial<<<nTiles, 256, 0, stream>>>(cnt, part, N);
        k_scan_top<<<1, 256, 0, stream>>>(part, nTiles);
        k_scan_final<<<nTiles, 256, 0, stream>>>(cnt, part, offs, N);

        unsigned int* csr;
        if (can_bin) {
            csr = csr_bin;
            k_bucket_base<<<(NB + bs - 1) / bs, bs, 0, stream>>>(offs, cur, NB);
            int binGrid = (E + ATILE - 1) / ATILE;
            k_bin<<<binGrid, 256, 0, stream>>>(src, dst, cur, pairs, E, NB);
            k_fill_local<<<NB, 256, 0, stream>>>(pairs, offs, csr, N, E);
        } else {
            csr = csr_dir;
            k_copy_i32<<<(N + bs - 1) / bs, bs, 0, stream>>>(offs, cur, N);
            k_fill_direct<<<(E + bs - 1) / bs, bs, 0, stream>>>(src, dst, cur, csr, E);
        }

        long long t_ag = (long long)N * 64;
        if (can_bf) {
            long long n8 = (long long)N * (FEAT / 8);
            k_cvt_bf16<<<(int)((n8 + bs - 1) / bs), bs, 0, stream>>>(x, xbf, n8);
            k_cvt_w<<<(FEAT * FEAT + bs - 1) / bs, bs, 0, stream>>>(W, wbf);
            k_aggregate_bf<<<(int)((t_ag + bs - 1) / bs), bs, 0, stream>>>(
                x, xbf, dinv, offs, cnt, csr, out, N);
            k_gemm_mfma<<<(N + 127) / 128, 256, 0, stream>>>(out, wbf, b, N);
        } else {
            k_aggregate<<<(int)((t_ag + bs - 1) / bs), bs, 0, stream>>>(
                x, dinv, offs, cnt, csr, out, N);
            k_gemm_inplace<<<(N + 15) / 16, 256, 0, stream>>>(out, W, b, N);
        }
    } else {
        float* deg = (float*)d_ws;
        k_deg_initf<<<(N + bs - 1) / bs, bs, 0, stream>>>(deg, N);
        k_deg_countf<<<(E + bs - 1) / bs, bs, 0, stream>>>(dst, deg, E);
        k_rsqrtf_<<<(N + bs - 1) / bs, bs, 0, stream>>>(deg, N);
        long long t_sl = (long long)N * 32;
        k_selfloop<<<(int)((t_sl + bs - 1) / bs), bs, 0, stream>>>(x, deg, out, N);
        long long t_sc = (long long)E * 64;
        k_scatter<<<(int)((t_sc + bs - 1) / bs), bs, 0, stream>>>(src, dst, deg, x, out, E);
        k_gemm_inplace<<<(N + 15) / 16, 256, 0, stream>>>(out, W, b, N);
    }
}

// Round 7
// 290.978 us; speedup vs baseline: 10.4983x; 1.5667x over previous
//
#include <hip/hip_runtime.h>

#define FEAT 128
#define BSH 7
#define BNODES 128            // nodes per bucket = 1<<BSH
#define ATILE 4096            // edges per binning block
#define MAXNB 1024            // bin path requires NB <= 1024
#define STILE 1024

typedef __attribute__((ext_vector_type(8))) short bf16x8;
typedef __attribute__((ext_vector_type(4))) float f32x4;

// ======================= tiny kernels =======================
__global__ void k_zero_i32(int* __restrict__ p, int n) {
    int i = blockIdx.x * blockDim.x + threadIdx.x;
    if (i < n) p[i] = 0;
}

__global__ void k_count(const int* __restrict__ dst, int* __restrict__ cnt, int E) {
    int i = blockIdx.x * blockDim.x + threadIdx.x;
    if (i < E) atomicAdd(&cnt[dst[i]], 1);
}

__global__ void k_dinv(const int* __restrict__ cnt, float* __restrict__ dinv, int N) {
    int i = blockIdx.x * blockDim.x + threadIdx.x;
    if (i < N) dinv[i] = rsqrtf((float)cnt[i] + 1.0f);
}

__global__ void k_bucket_base(const int* __restrict__ offs, int* __restrict__ cur, int NB) {
    int b = blockIdx.x * blockDim.x + threadIdx.x;
    if (b < NB) cur[b] = offs[b << BSH];
}

__device__ inline unsigned int f2bf(float f) {
    unsigned int u = __float_as_uint(f);
    return (u + 0x7FFFu + ((u >> 16) & 1u)) >> 16;   // RNE
}

__global__ void k_cvt_bf16(const float* __restrict__ x, unsigned int* __restrict__ xbf,
                           long long n8) {
    long long i = (long long)blockIdx.x * blockDim.x + threadIdx.x;  // one per 8 floats
    if (i >= n8) return;
    float4 a = ((const float4*)x)[i * 2];
    float4 c = ((const float4*)x)[i * 2 + 1];
    uint4 o;
    o.x = f2bf(a.x) | (f2bf(a.y) << 16);
    o.y = f2bf(a.z) | (f2bf(a.w) << 16);
    o.z = f2bf(c.x) | (f2bf(c.y) << 16);
    o.w = f2bf(c.z) | (f2bf(c.w) << 16);
    ((uint4*)xbf)[i] = o;
}

// Wt[n][k] = bf16(W[k][n])
__global__ void k_cvt_w(const float* __restrict__ W, unsigned short* __restrict__ wt) {
    int i = blockIdx.x * blockDim.x + threadIdx.x;
    if (i >= FEAT * FEAT) return;
    int n = i >> 7, k = i & 127;
    wt[i] = (unsigned short)f2bf(W[k * FEAT + n]);
}

// ======================= bucket-level hist + scan (new fast preprocessing) =======================
__global__ __launch_bounds__(256) void k_hist_bucket(const int* __restrict__ dst,
                                                     int* __restrict__ bCnt, int E, int NB) {
    __shared__ int h[MAXNB];
    int tid = threadIdx.x;
    for (int i = tid; i < NB; i += 256) h[i] = 0;
    __syncthreads();
    int base = blockIdx.x * ATILE;
    int end = min(base + ATILE, E);
    for (int e = base + tid; e < end; e += 256)
        atomicAdd(&h[dst[e] >> BSH], 1);
    __syncthreads();
    for (int i = tid; i < NB; i += 256)
        if (h[i]) atomicAdd(&bCnt[i], h[i]);
}

// single block: exclusive scan of bCnt[0..NB) -> bOffs (and cur copy); bOffs[NB]=E
__global__ void k_scan_bucket(const int* __restrict__ bCnt, int* __restrict__ bOffs,
                              int* __restrict__ cur, int NB, int E) {
    __shared__ int s[256];
    int t = threadIdx.x;
    int carry = 0;
    for (int base = 0; base < NB; base += 256) {
        int i = base + t;
        int v = (i < NB) ? bCnt[i] : 0;
        s[t] = v; __syncthreads();
        for (int o = 1; o < 256; o <<= 1) {
            int add = (t >= o) ? s[t - o] : 0;
            __syncthreads();
            s[t] += add;
            __syncthreads();
        }
        if (i < NB) { int ex = s[t] - v + carry; bOffs[i] = ex; cur[i] = ex; }
        __syncthreads();
        carry += s[255];
        __syncthreads();
    }
    if (t == 0) bOffs[NB] = E;
}

// ======================= exclusive scan over cnt -> offs (fallback path) =======================
__global__ void k_scan_partial(const int* __restrict__ cnt, int* __restrict__ part, int N) {
    __shared__ int s[256];
    int base = blockIdx.x * STILE;
    int t = threadIdx.x;
    int sum = 0;
#pragma unroll
    for (int k = 0; k < 4; ++k) {
        int i = base + t * 4 + k;
        if (i < N) sum += cnt[i];
    }
    s[t] = sum; __syncthreads();
    for (int off = 128; off > 0; off >>= 1) {
        if (t < off) s[t] += s[t + off];
        __syncthreads();
    }
    if (t == 0) part[blockIdx.x] = s[0];
}

__global__ void k_scan_top(int* __restrict__ part, int nTiles) {
    __shared__ int s[256];
    int t = threadIdx.x;
    int carry = 0;
    for (int base = 0; base < nTiles; base += 256) {
        int i = base + t;
        int v = (i < nTiles) ? part[i] : 0;
        s[t] = v; __syncthreads();
        for (int o = 1; o < 256; o <<= 1) {
            int add = (t >= o) ? s[t - o] : 0;
            __syncthreads();
            s[t] += add;
            __syncthreads();
        }
        if (i < nTiles) part[i] = (s[t] - v) + carry;
        __syncthreads();
        carry += s[255];
        __syncthreads();
    }
}

__global__ void k_scan_final(const int* __restrict__ cnt, const int* __restrict__ part,
                             int* __restrict__ offs, int N) {
    __shared__ int s[256];
    int base = blockIdx.x * STILE;
    int t = threadIdx.x;
    int v[4]; int sum = 0;
#pragma unroll
    for (int k = 0; k < 4; ++k) {
        int i = base + t * 4 + k;
        v[k] = (i < N) ? cnt[i] : 0;
        sum += v[k];
    }
    s[t] = sum; __syncthreads();
    for (int o = 1; o < 256; o <<= 1) {
        int add = (t >= o) ? s[t - o] : 0;
        __syncthreads();
        s[t] += add;
        __syncthreads();
    }
    int excl = (s[t] - sum) + part[blockIdx.x];
#pragma unroll
    for (int k = 0; k < 4; ++k) {
        int i = base + t * 4 + k;
        if (i < N) offs[i] = excl;
        excl += v[k];
    }
}

// ======================= pass A: bin edges by dst bucket =======================
__global__ __launch_bounds__(256) void k_bin(const int* __restrict__ src,
                                             const int* __restrict__ dst,
                                             int* __restrict__ cur,
                                             unsigned int* __restrict__ pairs,
                                             int E, int NB) {
    __shared__ int hist[MAXNB];
    __shared__ int tbase[MAXNB];
    __shared__ int sc[256];
    __shared__ unsigned int stM[ATILE];
    __shared__ unsigned short stB[ATILE];

    int tid = threadIdx.x;
    int tileBase = blockIdx.x * ATILE;
    int tileCnt = min(ATILE, E - tileBase);

    for (int i = tid; i < NB; i += 256) hist[i] = 0;
    __syncthreads();

    unsigned int pk[16]; unsigned short bk[16]; unsigned short rk[16];
#pragma unroll
    for (int k = 0; k < 16; ++k) {
        int e = tileBase + k * 256 + tid;
        if (e < E) {
            int s = src[e], d = dst[e];
            int b = d >> BSH;
            int r = atomicAdd(&hist[b], 1);
            pk[k] = (unsigned int)s | ((unsigned int)(d & (BNODES - 1)) << 24);
            bk[k] = (unsigned short)b;
            rk[k] = (unsigned short)r;
        }
    }
    __syncthreads();

    int per = (NB + 255) / 256;
    int myBase = tid * per;
    int partial = 0;
    for (int i = 0; i < per; ++i) {
        int idx = myBase + i;
        if (idx < NB) partial += hist[idx];
    }
    sc[tid] = partial;
    __syncthreads();
    for (int o = 1; o < 256; o <<= 1) {
        int add = (tid >= o) ? sc[tid - o] : 0;
        __syncthreads();
        sc[tid] += add;
        __syncthreads();
    }
    int run = (tid == 0) ? 0 : sc[tid - 1];
    for (int i = 0; i < per; ++i) {
        int idx = myBase + i;
        if (idx < NB) {
            int c = hist[idx];
            hist[idx] = run;
            if (c > 0) {
                int g = atomicAdd(&cur[idx], c);
                tbase[idx] = g - run;
            }
            run += c;
        }
    }
    __syncthreads();

#pragma unroll
    for (int k = 0; k < 16; ++k) {
        int e = tileBase + k * 256 + tid;
        if (e < E) {
            int slot = hist[bk[k]] + (int)rk[k];
            stM[slot] = pk[k];
            stB[slot] = bk[k];
        }
    }
    __syncthreads();

    for (int s = tid; s < tileCnt; s += 256) {
        int gpos = tbase[stB[s]] + s;
        pairs[gpos] = stM[s];
    }
}

// ======================= pass B (new): per-bucket cnt/offs/dinv + CSR fill =======================
__global__ __launch_bounds__(256) void k_fill_local2(const unsigned int* __restrict__ pairs,
                                                     const int* __restrict__ bOffs,
                                                     unsigned int* __restrict__ csr,
                                                     int* __restrict__ g_cnt,
                                                     int* __restrict__ g_offs,
                                                     float* __restrict__ g_dinv,
                                                     int N) {
    __shared__ int lcnt[BNODES];
    __shared__ int lexcl[BNODES];
    __shared__ int lcur[BNODES];
    int b = blockIdx.x;
    int node0 = b << BSH;
    int nn = min(BNODES, N - node0);
    int tid = threadIdx.x;
    int bstart = bOffs[b], bend = bOffs[b + 1];

    if (tid < BNODES) lcnt[tid] = 0;
    __syncthreads();
    for (int i = bstart + tid; i < bend; i += 256)
        atomicAdd(&lcnt[pairs[i] >> 24], 1);
    __syncthreads();
    if (tid < BNODES) lexcl[tid] = lcnt[tid];
    __syncthreads();
    for (int o = 1; o < BNODES; o <<= 1) {
        int add = (tid < BNODES && tid >= o) ? lexcl[tid - o] : 0;
        __syncthreads();
        if (tid < BNODES) lexcl[tid] += add;
        __syncthreads();
    }
    if (tid < BNODES) {
        int ex = bstart + lexcl[tid] - lcnt[tid];   // exclusive global start for node
        lcur[tid] = ex;
        if (tid < nn) {
            g_cnt[node0 + tid] = lcnt[tid];
            g_offs[node0 + tid] = ex;
            g_dinv[node0 + tid] = rsqrtf((float)lcnt[tid] + 1.0f);
        }
    }
    __syncthreads();
    for (int i = bstart + tid; i < bend; i += 256) {
        unsigned int p = pairs[i];
        int dl = (int)(p >> 24);
        int pos = atomicAdd(&lcur[dl], 1);
        csr[pos] = p & 0xFFFFFFu;
    }
}

// ======================= pass B (old): bucket-local CSR fill (tier B) =======================
__global__ __launch_bounds__(256) void k_fill_local(const unsigned int* __restrict__ pairs,
                                                    const int* __restrict__ offs,
                                                    unsigned int* __restrict__ csr,
                                                    int N, int E) {
    __shared__ int lcur[BNODES];
    int b = blockIdx.x;
    int node0 = b << BSH;
    int nn = min(BNODES, N - node0);
    int tid = threadIdx.x;
    for (int i = tid; i < nn; i += 256) lcur[i] = offs[node0 + i];
    __syncthreads();
    int start = offs[node0];
    int end = (node0 + BNODES >= N) ? E : offs[node0 + BNODES];
    for (int i = start + tid; i < end; i += 256) {
        unsigned int p = pairs[i];
        int dl = (int)(p >> 24);
        int pos = atomicAdd(&lcur[dl], 1);
        csr[pos] = p & 0xFFFFFFu;
    }
}

// ======================= aggregation (bf16 in, bf16 out): one wave per node =======================
__global__ __launch_bounds__(256) void k_aggregate_bf2(const unsigned int* __restrict__ xbf,
                                                       const float* __restrict__ dinv,
                                                       const int* __restrict__ offs,
                                                       const int* __restrict__ cnt,
                                                       const unsigned int* __restrict__ csr,
                                                       unsigned int* __restrict__ aggbf,
                                                       int N) {
    int wid = (blockIdx.x * blockDim.x + threadIdx.x) >> 6;
    int lane = threadIdx.x & 63;
    if (wid >= N) return;
    int n = __builtin_amdgcn_readfirstlane(wid);

    float di = dinv[n];
    int start = offs[n];
    int m = cnt[n];

    // self-loop from bf16 x
    unsigned int wself = xbf[(size_t)n * 64 + lane];
    float sl = di * di;
    float2 acc = make_float2(sl * __uint_as_float(wself << 16),
                             sl * __uint_as_float(wself & 0xFFFF0000u));

    int i = 0;
    for (; i + 8 <= m; i += 8) {
        int s[8]; float nr[8]; unsigned int w[8];
#pragma unroll
        for (int u = 0; u < 8; ++u) s[u] = (int)csr[start + i + u];
#pragma unroll
        for (int u = 0; u < 8; ++u) w[u] = xbf[(size_t)s[u] * 64 + lane];
#pragma unroll
        for (int u = 0; u < 8; ++u) nr[u] = dinv[s[u]] * di;
#pragma unroll
        for (int u = 0; u < 8; ++u) {
            acc.x += nr[u] * __uint_as_float(w[u] << 16);
            acc.y += nr[u] * __uint_as_float(w[u] & 0xFFFF0000u);
        }
    }
    for (; i + 4 <= m; i += 4) {
        int s0 = (int)csr[start + i];
        int s1 = (int)csr[start + i + 1];
        int s2 = (int)csr[start + i + 2];
        int s3 = (int)csr[start + i + 3];
        float n0 = dinv[s0] * di, n1 = dinv[s1] * di, n2 = dinv[s2] * di, n3 = dinv[s3] * di;
        unsigned int w0 = xbf[(size_t)s0 * 64 + lane];
        unsigned int w1 = xbf[(size_t)s1 * 64 + lane];
        unsigned int w2 = xbf[(size_t)s2 * 64 + lane];
        unsigned int w3 = xbf[(size_t)s3 * 64 + lane];
        acc.x += n0 * __uint_as_float(w0 << 16);
        acc.y += n0 * __uint_as_float(w0 & 0xFFFF0000u);
        acc.x += n1 * __uint_as_float(w1 << 16);
        acc.y += n1 * __uint_as_float(w1 & 0xFFFF0000u);
        acc.x += n2 * __uint_as_float(w2 << 16);
        acc.y += n2 * __uint_as_float(w2 & 0xFFFF0000u);
        acc.x += n3 * __uint_as_float(w3 << 16);
        acc.y += n3 * __uint_as_float(w3 & 0xFFFF0000u);
    }
    for (; i < m; ++i) {
        int s0 = (int)csr[start + i];
        float n0 = dinv[s0] * di;
        unsigned int w0 = xbf[(size_t)s0 * 64 + lane];
        acc.x += n0 * __uint_as_float(w0 << 16);
        acc.y += n0 * __uint_as_float(w0 & 0xFFFF0000u);
    }
    aggbf[(size_t)n * 64 + lane] = f2bf(acc.x) | (f2bf(acc.y) << 16);
}

// ======================= aggregation (bf16 gather, fp32 out) — tier B =======================
__global__ __launch_bounds__(256) void k_aggregate_bf(const float* __restrict__ x,
                                                      const unsigned int* __restrict__ xbf,
                                                      const float* __restrict__ dinv,
                                                      const int* __restrict__ offs,
                                                      const int* __restrict__ cnt,
                                                      const unsigned int* __restrict__ csr,
                                                      float* __restrict__ out, int N) {
    int wid = (blockIdx.x * blockDim.x + threadIdx.x) >> 6;
    int lane = threadIdx.x & 63;
    if (wid >= N) return;
    int n = __builtin_amdgcn_readfirstlane(wid);

    float di = dinv[n];
    int start = offs[n];
    int m = cnt[n];

    float2 a = ((const float2*)(x + (size_t)n * FEAT))[lane];
    float sl = di * di;
    float2 acc = make_float2(a.x * sl, a.y * sl);

    int i = 0;
    for (; i + 4 <= m; i += 4) {
        int s0 = (int)csr[start + i];
        int s1 = (int)csr[start + i + 1];
        int s2 = (int)csr[start + i + 2];
        int s3 = (int)csr[start + i + 3];
        float n0 = dinv[s0] * di, n1 = dinv[s1] * di, n2 = dinv[s2] * di, n3 = dinv[s3] * di;
        unsigned int w0 = xbf[(size_t)s0 * 64 + lane];
        unsigned int w1 = xbf[(size_t)s1 * 64 + lane];
        unsigned int w2 = xbf[(size_t)s2 * 64 + lane];
        unsigned int w3 = xbf[(size_t)s3 * 64 + lane];
        acc.x += n0 * __uint_as_float(w0 << 16);
        acc.y += n0 * __uint_as_float(w0 & 0xFFFF0000u);
        acc.x += n1 * __uint_as_float(w1 << 16);
        acc.y += n1 * __uint_as_float(w1 & 0xFFFF0000u);
        acc.x += n2 * __uint_as_float(w2 << 16);
        acc.y += n2 * __uint_as_float(w2 & 0xFFFF0000u);
        acc.x += n3 * __uint_as_float(w3 << 16);
        acc.y += n3 * __uint_as_float(w3 & 0xFFFF0000u);
    }
    for (; i < m; ++i) {
        int s0 = (int)csr[start + i];
        float n0 = dinv[s0] * di;
        unsigned int w0 = xbf[(size_t)s0 * 64 + lane];
        acc.x += n0 * __uint_as_float(w0 << 16);
        acc.y += n0 * __uint_as_float(w0 & 0xFFFF0000u);
    }
    ((float2*)(out + (size_t)n * FEAT))[lane] = acc;
}

// ======================= aggregation (fp32) — tier C =======================
__global__ __launch_bounds__(256) void k_aggregate(const float* __restrict__ x,
                                                   const float* __restrict__ dinv,
                                                   const int* __restrict__ offs,
                                                   const int* __restrict__ cnt,
                                                   const unsigned int* __restrict__ csr,
                                                   float* __restrict__ out, int N) {
    int wid = (blockIdx.x * blockDim.x + threadIdx.x) >> 6;
    int lane = threadIdx.x & 63;
    if (wid >= N) return;
    int n = __builtin_amdgcn_readfirstlane(wid);

    float di = dinv[n];
    int start = offs[n];
    int m = cnt[n];

    float2 a = ((const float2*)(x + (size_t)n * FEAT))[lane];
    float sl = di * di;
    float2 acc = make_float2(a.x * sl, a.y * sl);

    int i = 0;
    for (; i + 4 <= m; i += 4) {
        int s0 = (int)csr[start + i];
        int s1 = (int)csr[start + i + 1];
        int s2 = (int)csr[start + i + 2];
        int s3 = (int)csr[start + i + 3];
        float n0 = dinv[s0] * di, n1 = dinv[s1] * di, n2 = dinv[s2] * di, n3 = dinv[s3] * di;
        float2 v0 = ((const float2*)(x + (size_t)s0 * FEAT))[lane];
        float2 v1 = ((const float2*)(x + (size_t)s1 * FEAT))[lane];
        float2 v2 = ((const float2*)(x + (size_t)s2 * FEAT))[lane];
        float2 v3 = ((const float2*)(x + (size_t)s3 * FEAT))[lane];
        acc.x += n0 * v0.x; acc.y += n0 * v0.y;
        acc.x += n1 * v1.x; acc.y += n1 * v1.y;
        acc.x += n2 * v2.x; acc.y += n2 * v2.y;
        acc.x += n3 * v3.x; acc.y += n3 * v3.y;
    }
    for (; i < m; ++i) {
        int s0 = (int)csr[start + i];
        float n0 = dinv[s0] * di;
        float2 v0 = ((const float2*)(x + (size_t)s0 * FEAT))[lane];
        acc.x += n0 * v0.x; acc.y += n0 * v0.y;
    }
    ((float2*)(out + (size_t)n * FEAT))[lane] = acc;
}

// ======================= MFMA GEMM (bf16 A from aggbf): out = aggbf @ Wt^T + b =======================
__global__ __launch_bounds__(256) void k_gemm_mfma2(const unsigned short* __restrict__ abf,
                                                    const unsigned short* __restrict__ wt,
                                                    const float* __restrict__ bias,
                                                    float* __restrict__ out, int N) {
    int tid = threadIdx.x;
    int wave = tid >> 6, l = tid & 63;
    int lm = l & 15, lg = l >> 4;
    int rowA = blockIdx.x * 128 + wave * 32;

    f32x4 acc[2][8];
#pragma unroll
    for (int mt = 0; mt < 2; ++mt)
#pragma unroll
        for (int nt = 0; nt < 8; ++nt)
            acc[mt][nt] = (f32x4){0.f, 0.f, 0.f, 0.f};

#pragma unroll
    for (int kk = 0; kk < 4; ++kk) {
        int k = kk * 32 + lg * 8;
        bf16x8 afr[2];
#pragma unroll
        for (int mt = 0; mt < 2; ++mt) {
            int r = rowA + mt * 16 + lm;
            if (r < N)
                afr[mt] = *(const bf16x8*)(abf + (size_t)r * FEAT + k);
            else
                afr[mt] = (bf16x8){0, 0, 0, 0, 0, 0, 0, 0};
        }
#pragma unroll
        for (int nt = 0; nt < 8; ++nt) {
            int col = nt * 16 + lm;
            bf16x8 bfr = *(const bf16x8*)(wt + (size_t)col * FEAT + k);
            acc[0][nt] = __builtin_amdgcn_mfma_f32_16x16x32_bf16(afr[0], bfr, acc[0][nt], 0, 0, 0);
            acc[1][nt] = __builtin_amdgcn_mfma_f32_16x16x32_bf16(afr[1], bfr, acc[1][nt], 0, 0, 0);
        }
    }

#pragma unroll
    for (int nt = 0; nt < 8; ++nt) {
        int col = nt * 16 + lm;
        float bv = bias[col];
#pragma unroll
        for (int mt = 0; mt < 2; ++mt) {
#pragma unroll
            for (int r = 0; r < 4; ++r) {
                int row = rowA + mt * 16 + lg * 4 + r;
                if (row < N) out[(size_t)row * FEAT + col] = acc[mt][nt][r] + bv;
            }
        }
    }
}

// ======================= MFMA GEMM (in-place, fp32 A) — tier B =======================
__global__ __launch_bounds__(256) void k_gemm_mfma(float* __restrict__ out,
                                                   const unsigned short* __restrict__ wt,
                                                   const float* __restrict__ b, int N) {
    int tid = threadIdx.x;
    int wave = tid >> 6, l = tid & 63;
    int lm = l & 15, lg = l >> 4;
    int rowA = blockIdx.x * 128 + wave * 32;

    f32x4 acc[2][8];
#pragma unroll
    for (int mt = 0; mt < 2; ++mt)
#pragma unroll
        for (int nt = 0; nt < 8; ++nt)
            acc[mt][nt] = (f32x4){0.f, 0.f, 0.f, 0.f};

#pragma unroll
    for (int kk = 0; kk < 4; ++kk) {
        int k = kk * 32 + lg * 8;
        bf16x8 afr[2];
#pragma unroll
        for (int mt = 0; mt < 2; ++mt) {
            int r = rowA + mt * 16 + lm;
            float4 f0 = make_float4(0.f, 0.f, 0.f, 0.f);
            float4 f1 = make_float4(0.f, 0.f, 0.f, 0.f);
            if (r < N) {
                const float* p = out + (size_t)r * FEAT + k;
                f0 = *(const float4*)p;
                f1 = *(const float4*)(p + 4);
            }
            afr[mt][0] = (short)f2bf(f0.x);
            afr[mt][1] = (short)f2bf(f0.y);
            afr[mt][2] = (short)f2bf(f0.z);
            afr[mt][3] = (short)f2bf(f0.w);
            afr[mt][4] = (short)f2bf(f1.x);
            afr[mt][5] = (short)f2bf(f1.y);
            afr[mt][6] = (short)f2bf(f1.z);
            afr[mt][7] = (short)f2bf(f1.w);
        }
#pragma unroll
        for (int nt = 0; nt < 8; ++nt) {
            int col = nt * 16 + lm;
            bf16x8 bfr = *(const bf16x8*)(wt + (size_t)col * FEAT + k);
            acc[0][nt] = __builtin_amdgcn_mfma_f32_16x16x32_bf16(afr[0], bfr, acc[0][nt], 0, 0, 0);
            acc[1][nt] = __builtin_amdgcn_mfma_f32_16x16x32_bf16(afr[1], bfr, acc[1][nt], 0, 0, 0);
        }
    }

#pragma unroll
    for (int nt = 0; nt < 8; ++nt) {
        int col = nt * 16 + lm;
        float bv = b[col];
#pragma unroll
        for (int mt = 0; mt < 2; ++mt) {
#pragma unroll
            for (int r = 0; r < 4; ++r) {
                int row = rowA + mt * 16 + lg * 4 + r;
                if (row < N) out[(size_t)row * FEAT + col] = acc[mt][nt][r] + bv;
            }
        }
    }
}

// ======================= fp32 GEMM — tier C/D =======================
__global__ __launch_bounds__(256) void k_gemm_inplace(float* __restrict__ out,
                                                      const float* __restrict__ W,
                                                      const float* __restrict__ b, int N) {
    __shared__ float Wl[FEAT * FEAT];
    int tid = threadIdx.x;
    for (int i = tid; i < FEAT * FEAT / 4; i += 256)
        ((float4*)Wl)[i] = ((const float4*)W)[i];
    __syncthreads();

    int j = tid & 127;
    int half = tid >> 7;
    int row0 = blockIdx.x * 16 + half * 8;
    row0 = __builtin_amdgcn_readfirstlane(row0);

    float bj = b[j];
    float acc[8];
#pragma unroll
    for (int r = 0; r < 8; ++r) acc[r] = bj;

    const float* Y = out + (size_t)row0 * FEAT;
    bool full = (row0 + 8 <= N);
    if (full) {
        for (int f4 = 0; f4 < FEAT; f4 += 4) {
            float w0 = Wl[(f4 + 0) * FEAT + j];
            float w1 = Wl[(f4 + 1) * FEAT + j];
            float w2 = Wl[(f4 + 2) * FEAT + j];
            float w3 = Wl[(f4 + 3) * FEAT + j];
#pragma unroll
            for (int r = 0; r < 8; ++r) {
                float4 y = *(const float4*)&Y[(size_t)r * FEAT + f4];
                acc[r] += w0 * y.x + w1 * y.y + w2 * y.z + w3 * y.w;
            }
        }
    } else {
        for (int f = 0; f < FEAT; ++f) {
            float w = Wl[f * FEAT + j];
            for (int r = 0; r < 8; ++r)
                if (row0 + r < N) acc[r] += w * Y[(size_t)r * FEAT + f];
        }
    }
    __syncthreads();
    if (full) {
#pragma unroll
        for (int r = 0; r < 8; ++r) out[(size_t)(row0 + r) * FEAT + j] = acc[r];
    } else {
        for (int r = 0; r < 8; ++r)
            if (row0 + r < N) out[(size_t)(row0 + r) * FEAT + j] = acc[r];
    }
}

// ======================= misc fallbacks =======================
__global__ void k_fill_direct(const int* __restrict__ src, const int* __restrict__ dst,
                              int* __restrict__ cur, unsigned int* __restrict__ csr, int E) {
    int e = blockIdx.x * blockDim.x + threadIdx.x;
    if (e < E) {
        int d = dst[e];
        int p = atomicAdd(&cur[d], 1);
        csr[p] = (unsigned int)src[e];
    }
}
__global__ void k_copy_i32(const int* __restrict__ a, int* __restrict__ b, int n) {
    int i = blockIdx.x * blockDim.x + threadIdx.x;
    if (i < n) b[i] = a[i];
}
__global__ void k_deg_initf(float* __restrict__ deg, int N) {
    int i = blockIdx.x * blockDim.x + threadIdx.x;
    if (i < N) deg[i] = 1.0f;
}
__global__ void k_deg_countf(const int* __restrict__ dst, float* __restrict__ deg, int E) {
    int i = blockIdx.x * blockDim.x + threadIdx.x;
    if (i < E) atomicAdd(&deg[dst[i]], 1.0f);
}
__global__ void k_rsqrtf_(float* __restrict__ deg, int N) {
    int i = blockIdx.x * blockDim.x + threadIdx.x;
    if (i < N) deg[i] = rsqrtf(deg[i]);
}
__global__ void k_selfloop(const float* __restrict__ x, const float* __restrict__ dinv,
                           float* __restrict__ out, int N) {
    int t = blockIdx.x * blockDim.x + threadIdx.x;
    int n = t >> 5, c = t & 31;
    if (n >= N) return;
    float s = dinv[n]; s *= s;
    float4 v = ((const float4*)(x + (size_t)n * FEAT))[c];
    v.x *= s; v.y *= s; v.z *= s; v.w *= s;
    ((float4*)(out + (size_t)n * FEAT))[c] = v;
}
__global__ void k_scatter(const int* __restrict__ src, const int* __restrict__ dst,
                          const float* __restrict__ dinv, const float* __restrict__ x,
                          float* __restrict__ out, int E) {
    long long gid = (long long)blockIdx.x * blockDim.x + threadIdx.x;
    long long e = gid >> 6;
    int lane = threadIdx.x & 63;
    if (e >= E) return;
    int s = src[e], d = dst[e];
    float nrm = dinv[s] * dinv[d];
    const float* xs = x + (size_t)s * FEAT;
    float* od = out + (size_t)d * FEAT;
    atomicAdd(&od[lane],      nrm * xs[lane]);
    atomicAdd(&od[lane + 64], nrm * xs[lane + 64]);
}

// ======================= launch =======================
extern "C" void kernel_launch(void* const* d_in, const int* in_sizes, int n_in,
                              void* d_out, int out_size, void* d_ws, size_t ws_size,
                              hipStream_t stream) {
    const float* x = (const float*)d_in[0];
    const int*   ei = (const int*)d_in[1];
    const float* W = (const float*)d_in[2];
    const float* b = (const float*)d_in[3];
    float* out = (float*)d_out;

    int N = in_sizes[0] / FEAT;
    int E = in_sizes[1] / 2;
    const int* src = ei;
    const int* dst = ei + E;

    const int bs = 256;
    int nTiles = (N + STILE - 1) / STILE;
    int NB = (N + BNODES - 1) >> BSH;
    int binGrid = (E + ATILE - 1) / ATILE;

    // ---- Tier A layout (256B-aligned bump allocation) ----
    size_t off = 0;
    auto take = [&](size_t bytes) {
        size_t r = off;
        off = (off + bytes + 255) & ~(size_t)255;
        return r;
    };
    size_t o_dinv  = take(4 * (size_t)N);
    size_t o_cnt   = take(4 * (size_t)N);
    size_t o_offs  = take(4 * (size_t)N);
    size_t o_bcnt  = take(4 * (size_t)NB);
    size_t o_boffs = take(4 * (size_t)(NB + 1));
    size_t o_cur   = take(4 * (size_t)NB);
    size_t o_pairs = take(4 * (size_t)E);
    size_t o_csr   = take(4 * (size_t)E);
    size_t o_xbf   = take(4 * (size_t)N * 64);
    size_t o_wbf   = take(2 * (size_t)FEAT * FEAT);
    size_t need_preA = off;
    size_t o_aggbf = take(4 * (size_t)N * 64);
    size_t need_A = off;

    bool okNB = (NB <= MAXNB) && (N <= (1 << 24));
    bool can_A = okNB && (ws_size >= need_A);

    if (can_A) {
        char* base = (char*)d_ws;
        float* dinv = (float*)(base + o_dinv);
        int* cnt  = (int*)(base + o_cnt);
        int* offs = (int*)(base + o_offs);
        int* bCnt = (int*)(base + o_bcnt);
        int* bOffs= (int*)(base + o_boffs);
        int* cur  = (int*)(base + o_cur);
        unsigned int* pairs = (unsigned int*)(base + o_pairs);
        unsigned int* csr   = (unsigned int*)(base + o_csr);
        unsigned int* xbf   = (unsigned int*)(base + o_xbf);
        unsigned short* wbf = (unsigned short*)(base + o_wbf);
        unsigned int* aggbf = (unsigned int*)(base + o_aggbf);

        k_zero_i32<<<(NB + bs - 1) / bs, bs, 0, stream>>>(bCnt, NB);
        k_hist_bucket<<<binGrid, 256, 0, stream>>>(dst, bCnt, E, NB);
        k_scan_bucket<<<1, 256, 0, stream>>>(bCnt, bOffs, cur, NB, E);
        k_bin<<<binGrid, 256, 0, stream>>>(src, dst, cur, pairs, E, NB);
        k_fill_local2<<<NB, 256, 0, stream>>>(pairs, bOffs, csr, cnt, offs, dinv, N);

        long long n8 = (long long)N * (FEAT / 8);
        k_cvt_bf16<<<(int)((n8 + bs - 1) / bs), bs, 0, stream>>>(x, xbf, n8);
        k_cvt_w<<<(FEAT * FEAT + bs - 1) / bs, bs, 0, stream>>>(W, wbf);

        long long t_ag = (long long)N * 64;
        k_aggregate_bf2<<<(int)((t_ag + bs - 1) / bs), bs, 0, stream>>>(
            xbf, dinv, offs, cnt, csr, aggbf, N);
        k_gemm_mfma2<<<(N + 127) / 128, 256, 0, stream>>>(
            (const unsigned short*)aggbf, wbf, b, out, N);
        return;
    }

    // ---- Tier B/C/D: R6 layouts and paths ----
    size_t need_direct = (4 * (size_t)N + nTiles + (size_t)E) * 4;
    size_t need_bin    = (4 * (size_t)N + nTiles + 2 * (size_t)E) * 4;
    size_t need_bf     = need_bin + (size_t)N * 64 * 4 + (size_t)FEAT * FEAT * 2;

    float* dinv = (float*)d_ws;
    int* cnt  = (int*)d_ws + N;
    int* offs = (int*)d_ws + 2 * (size_t)N;
    int* cur  = (int*)d_ws + 3 * (size_t)N;
    int* part = (int*)d_ws + 4 * (size_t)N;
    unsigned int* pairs = (unsigned int*)(part + nTiles);
    unsigned int* csr_bin = pairs + E;
    unsigned int* xbf = csr_bin + E;
    unsigned short* wbf = (unsigned short*)(xbf + (size_t)N * 64);
    unsigned int* csr_dir = pairs;

    bool can_bin    = (ws_size >= need_bin) && okNB;
    bool can_bf     = can_bin && (ws_size >= need_bf);
    bool can_direct = (ws_size >= need_direct);

    if (can_bin || can_direct) {
        k_zero_i32<<<(N + bs - 1) / bs, bs, 0, stream>>>(cnt, N);
        k_count<<<(E + bs - 1) / bs, bs, 0, stream>>>(dst, cnt, E);
        k_dinv<<<(N + bs - 1) / bs, bs, 0, stream>>>(cnt, dinv, N);
        k_scan_partial<<<nTiles, 256, 0, stream>>>(cnt, part, N);
        k_scan_top<<<1, 256, 0, stream>>>(part, nTiles);
        k_scan_final<<<nTiles, 256, 0, stream>>>(cnt, part, offs, N);

        unsigned int* csr;
        if (can_bin) {
            csr = csr_bin;
            k_bucket_base<<<(NB + bs - 1) / bs, bs, 0, stream>>>(offs, cur, NB);
            k_bin<<<binGrid, 256, 0, stream>>>(src, dst, cur, pairs, E, NB);
            k_fill_local<<<NB, 256, 0, stream>>>(pairs, offs, csr, N, E);
        } else {
            csr = csr_dir;
            k_copy_i32<<<(N + bs - 1) / bs, bs, 0, stream>>>(offs, cur, N);
            k_fill_direct<<<(E + bs - 1) / bs, bs, 0, stream>>>(src, dst, cur, csr, E);
        }

        long long t_ag = (long long)N * 64;
        if (can_bf) {
            long long n8 = (long long)N * (FEAT / 8);
            k_cvt_bf16<<<(int)((n8 + bs - 1) / bs), bs, 0, stream>>>(x, xbf, n8);
            k_cvt_w<<<(FEAT * FEAT + bs - 1) / bs, bs, 0, stream>>>(W, wbf);
            k_aggregate_bf<<<(int)((t_ag + bs - 1) / bs), bs, 0, stream>>>(
                x, xbf, dinv, offs, cnt, csr, out, N);
            k_gemm_mfma<<<(N + 127) / 128, 256, 0, stream>>>(out, wbf, b, N);
        } else {
            k_aggregate<<<(int)((t_ag + bs - 1) / bs), bs, 0, stream>>>(
                x, dinv, offs, cnt, csr, out, N);
            k_gemm_inplace<<<(N + 15) / 16, 256, 0, stream>>>(out, W, b, N);
        }
    } else {
        float* deg = (float*)d_ws;
        k_deg_initf<<<(N + bs - 1) / bs, bs, 0, stream>>>(deg, N);
        k_deg_countf<<<(E + bs - 1) / bs, bs, 0, stream>>>(dst, deg, E);
        k_rsqrtf_<<<(N + bs - 1) / bs, bs, 0, stream>>>(deg, N);
        long long t_sl = (long long)N * 32;
        k_selfloop<<<(int)((t_sl + bs - 1) / bs), bs, 0, stream>>>(x, deg, out, N);
        long long t_sc = (long long)E * 64;
        k_scatter<<<(int)((t_sc + bs - 1) / bs), bs, 0, stream>>>(src, dst, deg, x, out, E);
        k_gemm_inplace<<<(N + 15) / 16, 256, 0, stream>>>(out, W, b, N);
    }
}